// Round 11
// baseline (164.182 us; speedup 1.0000x reference)
//
#include <hip/hip_runtime.h>

#define DM 1024
#define NHEAD 16
#define DK 64
#define QLD 3072   // fused QKV row stride

typedef short bf16x8 __attribute__((ext_vector_type(8)));
typedef float f32x4 __attribute__((ext_vector_type(4)));

__device__ __forceinline__ unsigned short f2bf(float f) {
  union { float f; unsigned u; } v; v.f = f;
  return (unsigned short)((v.u + 0x7fffu + ((v.u >> 16) & 1u)) >> 16);
}
__device__ __forceinline__ float bf2f(unsigned short h) {
  union { unsigned u; float f; } v; v.u = ((unsigned)h) << 16; return v.f;
}
__device__ __forceinline__ float fexp2(float x) {   // bare v_exp_f32: args bounded, no fixup needed
  float r; asm("v_exp_f32 %0, %1" : "=v"(r) : "v"(x)); return r;
}

__device__ __forceinline__ void gld16(const void* g, void* l) {
  __builtin_amdgcn_global_load_lds((const __attribute__((address_space(1))) void*)g,
                                   (__attribute__((address_space(3))) void*)l, 16, 0, 0);
}

// kappa: key = K(slot) within each 64-tile; bijective. Matches swapped-QK register layout.
__device__ __forceinline__ int kappa(int p) {
  return (p & 32) + (((p & 7) >> 2) << 4) + (((p >> 3) & 3) << 2) + (p & 3);
}

// ---------------- fused prep: x conv + 4 weight convs + bias cat + tw ----------------
__global__ void k_prep(const float* __restrict__ x, const float* __restrict__ Wq,
                       const float* __restrict__ Wk, const float* __restrict__ Wv,
                       const float* __restrict__ Wo, const float* __restrict__ bq,
                       const float* __restrict__ bk, const float* __restrict__ bv,
                       const float* __restrict__ coords,
                       unsigned short* __restrict__ xb, unsigned short* __restrict__ Wcat,
                       unsigned short* __restrict__ Wob, float* __restrict__ bcat,
                       float* __restrict__ tw, unsigned short* __restrict__ twb,
                       int M, int S, float QS) {
  const int nx = M * DM / 4;       // x float4 count
  const int nw = DM * DM / 4;      // per-weight float4 count
  const int total = nx + 4 * nw;
  int gid = blockIdx.x * 256 + threadIdx.x;

  auto conv4 = [&](const float* src, unsigned short* dst, int idx, float sc) {
    float4 v = *(const float4*)(src + idx * 4);
    ushort4 o;
    o.x = f2bf(v.x * sc); o.y = f2bf(v.y * sc);
    o.z = f2bf(v.z * sc); o.w = f2bf(v.w * sc);
    *(ushort4*)(dst + idx * 4) = o;
  };

  if (gid < nx) { conv4(x, xb, gid, 1.0f); return; }
  if (gid < nx + nw) { conv4(Wq, Wcat, gid - nx, QS); return; }
  if (gid < nx + 2 * nw) { conv4(Wk, Wcat + DM * DM, gid - nx - nw, 1.0f); return; }
  if (gid < nx + 3 * nw) { conv4(Wv, Wcat + 2 * DM * DM, gid - nx - 2 * nw, 1.0f); return; }
  if (gid < total) { conv4(Wo, Wob, gid - nx - 3 * nw, 1.0f); return; }

  int r = gid - total;
  if (r < 3 * DM) {
    float v = (r < DM) ? bq[r] * QS : (r < 2 * DM ? bk[r - DM] : bv[r - 2 * DM]);
    bcat[r] = v;
    return;
  }
  r -= 3 * DM;
  if (r < S) {
    auto twval = [&](int k) {
      float a = (k > 0)     ? fabsf(coords[k] - coords[k - 1]) : 0.f;
      float b = (k < S - 1) ? fabsf(coords[k + 1] - coords[k]) : 0.f;
      return 0.5f * (a + b);
    };
    tw[r] = twval(r);
    int key = (r & ~63) + kappa(r & 63);
    twb[r] = f2bf(twval(key));
  }
}

// ---------------- GEMM: C[M,N] = A[M,K] * B[N,K]^T + bias ----------------
// T2 XOR-swizzled LDS (pre-swizzled gld16 source + swizzled frag reads).
#define BM 128
#define BN 128
#define BKK 64

template<int OUTF32>
__global__ __launch_bounds__(256)
void gemm_bt(const unsigned short* __restrict__ A, const unsigned short* __restrict__ B,
             const float* __restrict__ bias, void* __restrict__ C,
             int M, int N, int K, int ldc) {
  __shared__ __align__(16) unsigned short sA[2][BM * BKK];
  __shared__ __align__(16) unsigned short sB[2][BN * BKK];
  const int tid = threadIdx.x;
  const int lane = tid & 63;
  const int wid = tid >> 6;
  const int rr = lane & 15, g = lane >> 4;
  const int nbn = N / BN;
  const int cpx = gridDim.x >> 3;
  const int bid = ((gridDim.x & 7) == 0) ? (blockIdx.x & 7) * cpx + (blockIdx.x >> 3)
                                         : blockIdx.x;
  const int bm = bid / nbn, bn = bid % nbn;
  const int wr = wid >> 1, wc = wid & 1;
  const int nkt = K / BKK;

  const unsigned short* Abase = A + (size_t)bm * BM * K;
  const unsigned short* Bbase = B + (size_t)bn * BN * K;

  auto stage = [&](int buf, int kt) {
#pragma unroll
    for (int j = 0; j < 4; ++j) {
      int o = j * 256 + tid;
      int row = o >> 3;
      int cb = ((o & 7) * 16) ^ ((row & 7) << 4);   // inverse-swizzled source byte col
      gld16((const char*)(Abase + (size_t)row * K + kt * BKK) + cb, &sA[buf][o * 8]);
      gld16((const char*)(Bbase + (size_t)row * K + kt * BKK) + cb, &sB[buf][o * 8]);
    }
  };

  f32x4 acc[4][4] = {};
  stage(0, 0);
  int cur = 0;
  const int sw = (rr & 7) << 4;
  for (int kt = 0; kt < nkt; ++kt) {
    __syncthreads();
    if (kt + 1 < nkt) stage(cur ^ 1, kt + 1);
    const char* a0 = (const char*)&sA[cur][(wr * 64) * BKK];
    const char* b0 = (const char*)&sB[cur][(wc * 64) * BKK];
#pragma unroll
    for (int kk = 0; kk < 2; ++kk) {
      const int co = (kk * 64 + g * 16);
      bf16x8 af[4], bfr[4];
#pragma unroll
      for (int m = 0; m < 4; ++m)
        af[m] = *(const bf16x8*)(a0 + (m * 16 + rr) * 128 + (co ^ sw));
#pragma unroll
      for (int n = 0; n < 4; ++n)
        bfr[n] = *(const bf16x8*)(b0 + (n * 16 + rr) * 128 + (co ^ sw));
      __builtin_amdgcn_s_setprio(1);
#pragma unroll
      for (int m = 0; m < 4; ++m)
#pragma unroll
        for (int n = 0; n < 4; ++n)
          acc[m][n] = __builtin_amdgcn_mfma_f32_16x16x32_bf16(af[m], bfr[n], acc[m][n], 0, 0, 0);
      __builtin_amdgcn_s_setprio(0);
    }
    cur ^= 1;
  }

  const int crow0 = bm * BM + wr * 64;
  const int ccol0 = bn * BN + wc * 64;
#pragma unroll
  for (int n = 0; n < 4; ++n) {
    const int col = ccol0 + n * 16 + rr;
    const float bn_ = bias ? bias[col] : 0.f;
#pragma unroll
    for (int m = 0; m < 4; ++m)
#pragma unroll
      for (int r = 0; r < 4; ++r) {
        const int row = crow0 + m * 16 + g * 4 + r;
        float v = acc[m][n][r] + bn_;
        if (OUTF32) ((float*)C)[(size_t)row * ldc + col] = v;
        else ((unsigned short*)C)[(size_t)row * ldc + col] = f2bf(v);
      }
  }
}

// ---------------- V transpose + tw prescale + kappa permute ----------------
__global__ __launch_bounds__(256)
void k_transpose(const unsigned short* __restrict__ V, const float* __restrict__ tw,
                 unsigned short* __restrict__ Vt, int S, int ld) {
  __shared__ __align__(16) unsigned short t[64][72];
  __shared__ float tws[64];
  const int nst = S / 64;
  int st = blockIdx.x % nst;
  int bh = blockIdx.x / nst;
  int h = bh & (NHEAD - 1), b = bh / NHEAD;
  const unsigned short* src = V + ((size_t)b * S + st * 64) * ld + h * DK;
  unsigned short* dst = Vt + (size_t)bh * DK * S + st * 64;
  int tid = threadIdx.x;
  if (tid < 64) tws[tid] = tw[st * 64 + tid];
#pragma unroll
  for (int i = 0; i < 2; ++i) {
    int r = i * 32 + (tid >> 3);
    int c = (tid & 7) * 8;
    *(uint4*)&t[r][c] = *(const uint4*)&src[(size_t)r * ld + c];
  }
  __syncthreads();
#pragma unroll
  for (int i = 0; i < 2; ++i) {
    int d = i * 32 + (tid >> 3);
    int p0 = (tid & 7) * 8;
    unsigned short tmp[8];
#pragma unroll
    for (int j = 0; j < 8; ++j) {
      int kl = kappa(p0 + j);    // slot -> key within 64-tile
      tmp[j] = f2bf(bf2f(t[kl][d]) * tws[kl]);
    }
    *(uint4*)&dst[(size_t)d * S + p0] = *(const uint4*)&tmp[0];
  }
}

// ---------------- attention: swapped QK^T, K direct from global (L1/L2), V in LDS ----------------
// 4 waves x 32 q-rows = 128 q-rows per block; KVBLK=64; sV only (16 KB).
__global__ __launch_bounds__(256)
void k_attn(const unsigned short* __restrict__ QKV, const unsigned short* __restrict__ Vt,
            const unsigned short* __restrict__ twb, unsigned short* __restrict__ O, int S) {
  __shared__ __align__(16) unsigned short sV[2][64 * 64];
  const int tid = threadIdx.x, lane = tid & 63, wid = tid >> 6;
  const int rr = lane & 15, g = lane >> 4;
  const int nqt = S / 128;
  const int cpx = gridDim.x >> 3;
  const int swz = (blockIdx.x & 7) * cpx + (blockIdx.x >> 3);
  const int qt = swz % nqt;
  const int bh = swz / nqt;
  const int h = bh & (NHEAD - 1), b = bh / NHEAD;

  const unsigned short* Qbase = QKV + ((size_t)b * S + qt * 128 + wid * 32) * QLD + h * DK;
  const unsigned short* Kbase = QKV + (size_t)b * S * QLD + DM + h * DK;
  const unsigned short* Vbase = Vt + (size_t)bh * DK * S;

  bf16x8 aq[2][2];
#pragma unroll
  for (int qm = 0; qm < 2; ++qm) {
    aq[qm][0] = *(const bf16x8*)&Qbase[(size_t)(qm * 16 + rr) * QLD + g * 8];
    aq[qm][1] = *(const bf16x8*)&Qbase[(size_t)(qm * 16 + rr) * QLD + 32 + g * 8];
  }

  f32x4 acc[2][5] = {};
  const f32x4 z0 = {};

  auto stage = [&](int buf, int kt) {
#pragma unroll
    for (int j = 0; j < 2; ++j) {
      int o = j * 256 + tid;       // 512 chunks of 16B per V tile
      int row = o >> 3;
      int cb = ((o & 7) * 16) ^ ((row & 7) << 4);
      gld16((const char*)(Vbase + (size_t)row * S + kt * 64) + cb, &sV[buf][o * 8]);
    }
  };

  stage(0, 0);
  int cur = 0;
  const int nkt = S / 64;
  for (int kt = 0; kt < nkt; ++kt) {
    __syncthreads();
    if (kt + 1 < nkt) stage(cur ^ 1, kt + 1);

    // swapped scores: s[qm][f] = P[key=16f+4g+r][q=qm*16+rr]
    // K fragments straight from global — 8 KB tile, L1-resident after first wave
    f32x4 s[2][4];
#pragma unroll
    for (int f = 0; f < 4; ++f) {
      const unsigned short* krow = Kbase + (size_t)(kt * 64 + f * 16 + rr) * QLD;
      bf16x8 kA0 = *(const bf16x8*)&krow[g * 8];
      bf16x8 kA1 = *(const bf16x8*)&krow[32 + g * 8];
      __builtin_amdgcn_s_setprio(1);
#pragma unroll
      for (int qm = 0; qm < 2; ++qm) {
        f32x4 z = __builtin_amdgcn_mfma_f32_16x16x32_bf16(kA0, aq[qm][0], z0, 0, 0, 0);
        s[qm][f] = __builtin_amdgcn_mfma_f32_16x16x32_bf16(kA1, aq[qm][1], z, 0, 0, 0);
      }
      __builtin_amdgcn_s_setprio(0);
    }

    // p = exp2(s) in place (lane-local)
#pragma unroll
    for (int qm = 0; qm < 2; ++qm)
#pragma unroll
      for (int f = 0; f < 4; ++f)
#pragma unroll
        for (int r = 0; r < 4; ++r)
          s[qm][f][r] = fexp2(s[qm][f][r]);

    // pack P into A-frags in registers: slot kk*32+g*8+j -> (f=2kk+(j>>2), r=j&3)
    bf16x8 pa[2][2];
#pragma unroll
    for (int qm = 0; qm < 2; ++qm)
#pragma unroll
      for (int kk = 0; kk < 2; ++kk) {
        union { bf16x8 v; unsigned u[4]; } pk;
        asm("v_cvt_pk_bf16_f32 %0, %1, %2" : "=v"(pk.u[0]) : "v"(s[qm][2*kk][0]),   "v"(s[qm][2*kk][1]));
        asm("v_cvt_pk_bf16_f32 %0, %1, %2" : "=v"(pk.u[1]) : "v"(s[qm][2*kk][2]),   "v"(s[qm][2*kk][3]));
        asm("v_cvt_pk_bf16_f32 %0, %1, %2" : "=v"(pk.u[2]) : "v"(s[qm][2*kk+1][0]), "v"(s[qm][2*kk+1][1]));
        asm("v_cvt_pk_bf16_f32 %0, %1, %2" : "=v"(pk.u[3]) : "v"(s[qm][2*kk+1][2]), "v"(s[qm][2*kk+1][3]));
        pa[qm][kk] = pk.v;
      }

    // tw fragments for denominator (kappa-ordered, matches V slot order)
    bf16x8 tw0 = *(const bf16x8*)&twb[kt * 64 + g * 8];
    bf16x8 tw1 = *(const bf16x8*)&twb[kt * 64 + 32 + g * 8];

    // PV + denominator: V frags reused across both q-subtiles
#pragma unroll
    for (int kk = 0; kk < 2; ++kk) {
      __builtin_amdgcn_s_setprio(1);
#pragma unroll
      for (int n = 0; n < 4; ++n) {
        const int vrow = n * 16 + rr;
        const int cb = (kk * 64 + g * 16) ^ ((vrow & 7) << 4);
        bf16x8 bv = *(const bf16x8*)((const char*)&sV[cur][vrow * 64] + cb);
#pragma unroll
        for (int qm = 0; qm < 2; ++qm)
          acc[qm][n] = __builtin_amdgcn_mfma_f32_16x16x32_bf16(pa[qm][kk], bv, acc[qm][n], 0, 0, 0);
      }
#pragma unroll
      for (int qm = 0; qm < 2; ++qm)
        acc[qm][4] = __builtin_amdgcn_mfma_f32_16x16x32_bf16(pa[qm][kk], kk ? tw1 : tw0, acc[qm][4], 0, 0, 0);
      __builtin_amdgcn_s_setprio(0);
    }
    cur ^= 1;
  }

  unsigned short* Ob = O + ((size_t)b * S + qt * 128 + wid * 32) * DM + h * DK;
#pragma unroll
  for (int qm = 0; qm < 2; ++qm)
#pragma unroll
    for (int n = 0; n < 4; ++n)
#pragma unroll
      for (int r = 0; r < 4; ++r) {
        const int q = qm * 16 + g * 4 + r;
        const int d = n * 16 + rr;
        Ob[(size_t)q * DM + d] = f2bf(acc[qm][n][r] / acc[qm][4][r]);
      }
}

// ---------------- launch ----------------
extern "C" void kernel_launch(void* const* d_in, const int* in_sizes, int n_in,
                              void* d_out, int out_size, void* d_ws, size_t ws_size,
                              hipStream_t stream) {
  const float* x      = (const float*)d_in[0];
  const float* coords = (const float*)d_in[1];
  const float* Wq = (const float*)d_in[2];
  const float* bq = (const float*)d_in[3];
  const float* Wk = (const float*)d_in[4];
  const float* bk = (const float*)d_in[5];
  const float* Wv = (const float*)d_in[6];
  const float* bv = (const float*)d_in[7];
  const float* Wo = (const float*)d_in[8];
  const float* bo = (const float*)d_in[9];

  const int S = in_sizes[1];
  const int B = in_sizes[0] / (S * DM);
  const int M = B * S;
  const float QS = 0.18033688011112042f;   // log2(e)/8

  char* w = (char*)d_ws;
  size_t off = 0;
  unsigned short* xb   = (unsigned short*)(w + off); off += (size_t)M * DM * 2;
  unsigned short* Wcat = (unsigned short*)(w + off); off += (size_t)3 * DM * DM * 2;
  unsigned short* Wob  = (unsigned short*)(w + off); off += (size_t)DM * DM * 2;
  unsigned short* QKVb = (unsigned short*)(w + off); off += (size_t)M * QLD * 2;
  unsigned short* Vtb  = (unsigned short*)(w + off); off += (size_t)M * DM * 2;
  float* tw  = (float*)(w + off); off += (size_t)S * 4;
  unsigned short* twb = (unsigned short*)(w + off); off += (size_t)S * 2;
  float* bcat = (float*)(w + off); off += (size_t)3 * DM * 4;
  unsigned short* Ob = xb;   // alias: xb dead after QKV gemm
  (void)ws_size; (void)n_in; (void)out_size;

  // fused prep (x conv, 4 weight convs, bias cat, tw) — one launch
  {
    int nx = M * DM / 4, nw = DM * DM / 4;
    int total = nx + 4 * nw;
    int tail = 3 * DM + S;
    int gridp = total / 256 + (tail + 255) / 256;
    k_prep<<<gridp, 256, 0, stream>>>(x, Wq, Wk, Wv, Wo, bq, bk, bv, coords,
                                      xb, Wcat, Wob, bcat, tw, twb, M, S, QS);
  }

  // fused QKV projection: [M,1024] x [3072,1024]^T -> [M,3072]
  gemm_bt<0><<<(M / BM) * (3 * DM / BN), 256, 0, stream>>>(xb, Wcat, bcat, QKVb, M, 3 * DM, DM, QLD);

  // V transpose (+ tw prescale, kappa permute) + attention
  k_transpose<<<B * NHEAD * (S / 64), 256, 0, stream>>>(QKVb + 2 * DM, tw, Vtb, S, QLD);
  k_attn<<<B * NHEAD * (S / 128), 256, 0, stream>>>(QKVb, Vtb, twb, Ob, S);

  // output projection (f32 out)
  gemm_bt<1><<<(M / BM) * (DM / BN), 256, 0, stream>>>(Ob, Wob, bo, d_out, M, DM, DM, DM);
}

// Round 12
// 113.147 us; speedup vs baseline: 1.4511x; 1.4511x over previous
//
#include <hip/hip_runtime.h>

#define DM 1024
#define NHEAD 16
#define DK 64
#define QLD 3072   // fused QKV row stride

typedef short bf16x8 __attribute__((ext_vector_type(8)));
typedef float f32x4 __attribute__((ext_vector_type(4)));

__device__ __forceinline__ unsigned short f2bf(float f) {
  union { float f; unsigned u; } v; v.f = f;
  return (unsigned short)((v.u + 0x7fffu + ((v.u >> 16) & 1u)) >> 16);
}
__device__ __forceinline__ float bf2f(unsigned short h) {
  union { unsigned u; float f; } v; v.u = ((unsigned)h) << 16; return v.f;
}
__device__ __forceinline__ float fexp2(float x) {   // bare v_exp_f32: args bounded, no fixup needed
  float r; asm("v_exp_f32 %0, %1" : "=v"(r) : "v"(x)); return r;
}

__device__ __forceinline__ void gld16(const void* g, void* l) {
  __builtin_amdgcn_global_load_lds((const __attribute__((address_space(1))) void*)g,
                                   (__attribute__((address_space(3))) void*)l, 16, 0, 0);
}

// kappa: key = K(slot) within each 64-tile; bijective. Matches swapped-QK register layout.
__device__ __forceinline__ int kappa(int p) {
  return (p & 32) + (((p & 7) >> 2) << 4) + (((p >> 3) & 3) << 2) + (p & 3);
}

// ---------------- fused prep: x conv + 4 weight convs + bias cat + tw ----------------
__global__ void k_prep(const float* __restrict__ x, const float* __restrict__ Wq,
                       const float* __restrict__ Wk, const float* __restrict__ Wv,
                       const float* __restrict__ Wo, const float* __restrict__ bq,
                       const float* __restrict__ bk, const float* __restrict__ bv,
                       const float* __restrict__ coords,
                       unsigned short* __restrict__ xb, unsigned short* __restrict__ Wcat,
                       unsigned short* __restrict__ Wob, float* __restrict__ bcat,
                       float* __restrict__ tw, unsigned short* __restrict__ twb,
                       int M, int S, float QS) {
  const int nx = M * DM / 4;       // x float4 count
  const int nw = DM * DM / 4;      // per-weight float4 count
  const int total = nx + 4 * nw;
  int gid = blockIdx.x * 256 + threadIdx.x;

  auto conv4 = [&](const float* src, unsigned short* dst, int idx, float sc) {
    float4 v = *(const float4*)(src + idx * 4);
    ushort4 o;
    o.x = f2bf(v.x * sc); o.y = f2bf(v.y * sc);
    o.z = f2bf(v.z * sc); o.w = f2bf(v.w * sc);
    *(ushort4*)(dst + idx * 4) = o;
  };

  if (gid < nx) { conv4(x, xb, gid, 1.0f); return; }
  if (gid < nx + nw) { conv4(Wq, Wcat, gid - nx, QS); return; }
  if (gid < nx + 2 * nw) { conv4(Wk, Wcat + DM * DM, gid - nx - nw, 1.0f); return; }
  if (gid < nx + 3 * nw) { conv4(Wv, Wcat + 2 * DM * DM, gid - nx - 2 * nw, 1.0f); return; }
  if (gid < total) { conv4(Wo, Wob, gid - nx - 3 * nw, 1.0f); return; }

  int r = gid - total;
  if (r < 3 * DM) {
    float v = (r < DM) ? bq[r] * QS : (r < 2 * DM ? bk[r - DM] : bv[r - 2 * DM]);
    bcat[r] = v;
    return;
  }
  r -= 3 * DM;
  if (r < S) {
    auto twval = [&](int k) {
      float a = (k > 0)     ? fabsf(coords[k] - coords[k - 1]) : 0.f;
      float b = (k < S - 1) ? fabsf(coords[k + 1] - coords[k]) : 0.f;
      return 0.5f * (a + b);
    };
    tw[r] = twval(r);
    int key = (r & ~63) + kappa(r & 63);
    twb[r] = f2bf(twval(key));
  }
}

// ---------------- GEMM: C[M,N] = A[M,K] * B[N,K]^T + bias ----------------
// T2 XOR-swizzled LDS; bf16 path stores C via LDS restage for coalescing.
#define BM 128
#define BN 128
#define BKK 64

template<int OUTF32>
__global__ __launch_bounds__(256)
void gemm_bt(const unsigned short* __restrict__ A, const unsigned short* __restrict__ B,
             const float* __restrict__ bias, void* __restrict__ C,
             int M, int N, int K, int ldc) {
  __shared__ __align__(16) unsigned short smem[4][BM * BKK];   // [0..1]=A dbuf, [2..3]=B dbuf
  const int tid = threadIdx.x;
  const int lane = tid & 63;
  const int wid = tid >> 6;
  const int rr = lane & 15, g = lane >> 4;
  const int nbn = N / BN;
  const int cpx = gridDim.x >> 3;
  const int bid = ((gridDim.x & 7) == 0) ? (blockIdx.x & 7) * cpx + (blockIdx.x >> 3)
                                         : blockIdx.x;
  const int bm = bid / nbn, bn = bid % nbn;
  const int wr = wid >> 1, wc = wid & 1;
  const int nkt = K / BKK;

  const unsigned short* Abase = A + (size_t)bm * BM * K;
  const unsigned short* Bbase = B + (size_t)bn * BN * K;

  auto stage = [&](int buf, int kt) {
#pragma unroll
    for (int j = 0; j < 4; ++j) {
      int o = j * 256 + tid;
      int row = o >> 3;
      int cb = ((o & 7) * 16) ^ ((row & 7) << 4);   // inverse-swizzled source byte col
      gld16((const char*)(Abase + (size_t)row * K + kt * BKK) + cb, &smem[buf][o * 8]);
      gld16((const char*)(Bbase + (size_t)row * K + kt * BKK) + cb, &smem[2 + buf][o * 8]);
    }
  };

  f32x4 acc[4][4] = {};
  stage(0, 0);
  int cur = 0;
  const int sw = (rr & 7) << 4;
  for (int kt = 0; kt < nkt; ++kt) {
    __syncthreads();
    if (kt + 1 < nkt) stage(cur ^ 1, kt + 1);
    const char* a0 = (const char*)&smem[cur][(wr * 64) * BKK];
    const char* b0 = (const char*)&smem[2 + cur][(wc * 64) * BKK];
#pragma unroll
    for (int kk = 0; kk < 2; ++kk) {
      const int co = (kk * 64 + g * 16);
      bf16x8 af[4], bfr[4];
#pragma unroll
      for (int m = 0; m < 4; ++m)
        af[m] = *(const bf16x8*)(a0 + (m * 16 + rr) * 128 + (co ^ sw));
#pragma unroll
      for (int n = 0; n < 4; ++n)
        bfr[n] = *(const bf16x8*)(b0 + (n * 16 + rr) * 128 + (co ^ sw));
      __builtin_amdgcn_s_setprio(1);
#pragma unroll
      for (int m = 0; m < 4; ++m)
#pragma unroll
        for (int n = 0; n < 4; ++n)
          acc[m][n] = __builtin_amdgcn_mfma_f32_16x16x32_bf16(af[m], bfr[n], acc[m][n], 0, 0, 0);
      __builtin_amdgcn_s_setprio(0);
    }
    cur ^= 1;
  }

  const int crow0 = bm * BM + wr * 64;
  const int ccol0 = bn * BN + wc * 64;
  if (OUTF32) {
#pragma unroll
    for (int n = 0; n < 4; ++n) {
      const int col = ccol0 + n * 16 + rr;
      const float bn_ = bias ? bias[col] : 0.f;
#pragma unroll
      for (int m = 0; m < 4; ++m)
#pragma unroll
        for (int r = 0; r < 4; ++r) {
          const int row = crow0 + m * 16 + g * 4 + r;
          ((float*)C)[(size_t)row * ldc + col] = acc[m][n][r] + bn_;
        }
    }
  } else {
    // restage through LDS (row pad 136 shorts) for coalesced 16B stores
    unsigned short* L = &smem[0][0];   // 128*136 = 17408 shorts <= 32768
    __syncthreads();                   // all fragment reads of smem done
#pragma unroll
    for (int n = 0; n < 4; ++n) {
      const float bn_ = bias ? bias[ccol0 + n * 16 + rr] : 0.f;
#pragma unroll
      for (int m = 0; m < 4; ++m)
#pragma unroll
        for (int r = 0; r < 4; ++r)
          L[(wr * 64 + m * 16 + g * 4 + r) * 136 + wc * 64 + n * 16 + rr] =
              f2bf(acc[m][n][r] + bn_);
    }
    __syncthreads();
    unsigned short* Cb = (unsigned short*)C + (size_t)(bm * BM) * ldc + bn * BN;
#pragma unroll
    for (int i = 0; i < 8; ++i) {
      int o = i * 256 + tid;
      int row = o >> 4;
      int cc = (o & 15) * 8;
      uint4 v = *(const uint4*)&L[row * 136 + cc];
      *(uint4*)&Cb[(size_t)row * ldc + cc] = v;
    }
  }
}

// ---------------- V transpose + tw prescale + kappa permute ----------------
__global__ __launch_bounds__(256)
void k_transpose(const unsigned short* __restrict__ V, const float* __restrict__ tw,
                 unsigned short* __restrict__ Vt, int S, int ld) {
  __shared__ __align__(16) unsigned short t[64][72];
  __shared__ float tws[64];
  const int nst = S / 64;
  int st = blockIdx.x % nst;
  int bh = blockIdx.x / nst;
  int h = bh & (NHEAD - 1), b = bh / NHEAD;
  const unsigned short* src = V + ((size_t)b * S + st * 64) * ld + h * DK;
  unsigned short* dst = Vt + (size_t)bh * DK * S + st * 64;
  int tid = threadIdx.x;
  if (tid < 64) tws[tid] = tw[st * 64 + tid];
#pragma unroll
  for (int i = 0; i < 2; ++i) {
    int r = i * 32 + (tid >> 3);
    int c = (tid & 7) * 8;
    *(uint4*)&t[r][c] = *(const uint4*)&src[(size_t)r * ld + c];
  }
  __syncthreads();
#pragma unroll
  for (int i = 0; i < 2; ++i) {
    int d = i * 32 + (tid >> 3);
    int p0 = (tid & 7) * 8;
    unsigned short tmp[8];
#pragma unroll
    for (int j = 0; j < 8; ++j) {
      int kl = kappa(p0 + j);    // slot -> key within 64-tile
      tmp[j] = f2bf(bf2f(t[kl][d]) * tws[kl]);
    }
    *(uint4*)&dst[(size_t)d * S + p0] = *(const uint4*)&tmp[0];
  }
}

// ---------------- attention: swapped QK^T, fissioned schedule, KVBLK=128 ----------------
// 4 waves x 32 q-rows; per staged tile: QK both halves -> exp2 all -> pack+PV per half.
__global__ __launch_bounds__(256)
void k_attn(const unsigned short* __restrict__ QKV, const unsigned short* __restrict__ Vt,
            const unsigned short* __restrict__ twb, unsigned short* __restrict__ O, int S) {
  __shared__ __align__(16) unsigned short sK[2][128 * 64];   // 128 keys x 64 d
  __shared__ __align__(16) unsigned short sV[2][64 * 128];   // 64 d x 128 key-slots
  const int tid = threadIdx.x, lane = tid & 63, wid = tid >> 6;
  const int rr = lane & 15, g = lane >> 4;
  const int nqt = S / 128;
  const int cpx = gridDim.x >> 3;
  const int swz = (blockIdx.x & 7) * cpx + (blockIdx.x >> 3);
  const int qt = swz % nqt;
  const int bh = swz / nqt;
  const int h = bh & (NHEAD - 1), b = bh / NHEAD;

  const unsigned short* Qbase = QKV + ((size_t)b * S + qt * 128 + wid * 32) * QLD + h * DK;
  const unsigned short* Kbase = QKV + (size_t)b * S * QLD + DM + h * DK;
  const unsigned short* Vbase = Vt + (size_t)bh * DK * S;

  bf16x8 aq[2][2];
#pragma unroll
  for (int qm = 0; qm < 2; ++qm) {
    aq[qm][0] = *(const bf16x8*)&Qbase[(size_t)(qm * 16 + rr) * QLD + g * 8];
    aq[qm][1] = *(const bf16x8*)&Qbase[(size_t)(qm * 16 + rr) * QLD + 32 + g * 8];
  }

  f32x4 acc[2][5] = {};
  const f32x4 z0 = {};

  auto stage = [&](int buf, int kt) {
    // K: 128 rows x 128B, 1024 chunks
#pragma unroll
    for (int j = 0; j < 4; ++j) {
      int o = j * 256 + tid;
      int row = o >> 3;
      int cb = ((o & 7) * 16) ^ ((row & 7) << 4);
      gld16((const char*)(Kbase + (size_t)(kt * 128 + row) * QLD) + cb, &sK[buf][o * 8]);
    }
    // V: 64 rows x 256B, 1024 chunks (swizzle within each 128B half-row)
#pragma unroll
    for (int j = 0; j < 4; ++j) {
      int o = j * 256 + tid;
      int row = o >> 4;
      int cb = ((o & 15) * 16) ^ ((row & 7) << 4);
      gld16((const char*)(Vbase + (size_t)row * S + kt * 128) + cb, &sV[buf][o * 8]);
    }
  };

  stage(0, 0);
  int cur = 0;
  const int nkt = S / 128;
  const int swr = (rr & 7) << 4;
  for (int kt = 0; kt < nkt; ++kt) {
    __syncthreads();
    if (kt + 1 < nkt) stage(cur ^ 1, kt + 1);

    // ---- QK^T for BOTH halves (long MFMA stretch) ----
    f32x4 s[2][2][4];   // [half][qm][f]
#pragma unroll
    for (int half = 0; half < 2; ++half) {
#pragma unroll
      for (int f = 0; f < 4; ++f) {
        const int row = half * 64 + f * 16 + rr;
        bf16x8 kA0 = *(const bf16x8*)((const char*)&sK[cur][row * 64] + ((g * 16) ^ swr));
        bf16x8 kA1 = *(const bf16x8*)((const char*)&sK[cur][row * 64] + ((64 + g * 16) ^ swr));
        __builtin_amdgcn_s_setprio(1);
#pragma unroll
        for (int qm = 0; qm < 2; ++qm) {
          f32x4 z = __builtin_amdgcn_mfma_f32_16x16x32_bf16(kA0, aq[qm][0], z0, 0, 0, 0);
          s[half][qm][f] = __builtin_amdgcn_mfma_f32_16x16x32_bf16(kA1, aq[qm][1], z, 0, 0, 0);
        }
        __builtin_amdgcn_s_setprio(0);
      }
    }

    // ---- exp2 for all 128 keys (long VALU/trans stretch) ----
#pragma unroll
    for (int half = 0; half < 2; ++half)
#pragma unroll
      for (int qm = 0; qm < 2; ++qm)
#pragma unroll
        for (int f = 0; f < 4; ++f)
#pragma unroll
          for (int r = 0; r < 4; ++r)
            s[half][qm][f][r] = fexp2(s[half][qm][f][r]);

    // ---- pack + PV + denom per half ----
#pragma unroll
    for (int half = 0; half < 2; ++half) {
      bf16x8 pa[2][2];
#pragma unroll
      for (int qm = 0; qm < 2; ++qm)
#pragma unroll
        for (int kk = 0; kk < 2; ++kk) {
          union { bf16x8 v; unsigned u[4]; } pk;
          asm("v_cvt_pk_bf16_f32 %0, %1, %2" : "=v"(pk.u[0]) : "v"(s[half][qm][2*kk][0]),   "v"(s[half][qm][2*kk][1]));
          asm("v_cvt_pk_bf16_f32 %0, %1, %2" : "=v"(pk.u[1]) : "v"(s[half][qm][2*kk][2]),   "v"(s[half][qm][2*kk][3]));
          asm("v_cvt_pk_bf16_f32 %0, %1, %2" : "=v"(pk.u[2]) : "v"(s[half][qm][2*kk+1][0]), "v"(s[half][qm][2*kk+1][1]));
          asm("v_cvt_pk_bf16_f32 %0, %1, %2" : "=v"(pk.u[3]) : "v"(s[half][qm][2*kk+1][2]), "v"(s[half][qm][2*kk+1][3]));
          pa[qm][kk] = pk.v;
        }

      bf16x8 tw0 = *(const bf16x8*)&twb[kt * 128 + half * 64 + g * 8];
      bf16x8 tw1 = *(const bf16x8*)&twb[kt * 128 + half * 64 + 32 + g * 8];

#pragma unroll
      for (int kk = 0; kk < 2; ++kk) {
        __builtin_amdgcn_s_setprio(1);
#pragma unroll
        for (int n = 0; n < 4; ++n) {
          const int vrow = n * 16 + rr;
          const int cb = (half * 128 + kk * 64 + g * 16) ^ ((vrow & 7) << 4);
          bf16x8 bv = *(const bf16x8*)((const char*)&sV[cur][vrow * 128] + cb);
#pragma unroll
          for (int qm = 0; qm < 2; ++qm)
            acc[qm][n] = __builtin_amdgcn_mfma_f32_16x16x32_bf16(pa[qm][kk], bv, acc[qm][n], 0, 0, 0);
        }
#pragma unroll
        for (int qm = 0; qm < 2; ++qm)
          acc[qm][4] = __builtin_amdgcn_mfma_f32_16x16x32_bf16(pa[qm][kk], kk ? tw1 : tw0, acc[qm][4], 0, 0, 0);
        __builtin_amdgcn_s_setprio(0);
      }
    }
    cur ^= 1;
  }

  unsigned short* Ob = O + ((size_t)b * S + qt * 128 + wid * 32) * DM + h * DK;
#pragma unroll
  for (int qm = 0; qm < 2; ++qm)
#pragma unroll
    for (int n = 0; n < 4; ++n)
#pragma unroll
      for (int r = 0; r < 4; ++r) {
        const int q = qm * 16 + g * 4 + r;
        const int d = n * 16 + rr;
        Ob[(size_t)q * DM + d] = f2bf(acc[qm][n][r] / acc[qm][4][r]);
      }
}

// ---------------- launch ----------------
extern "C" void kernel_launch(void* const* d_in, const int* in_sizes, int n_in,
                              void* d_out, int out_size, void* d_ws, size_t ws_size,
                              hipStream_t stream) {
  const float* x      = (const float*)d_in[0];
  const float* coords = (const float*)d_in[1];
  const float* Wq = (const float*)d_in[2];
  const float* bq = (const float*)d_in[3];
  const float* Wk = (const float*)d_in[4];
  const float* bk = (const float*)d_in[5];
  const float* Wv = (const float*)d_in[6];
  const float* bv = (const float*)d_in[7];
  const float* Wo = (const float*)d_in[8];
  const float* bo = (const float*)d_in[9];

  const int S = in_sizes[1];
  const int B = in_sizes[0] / (S * DM);
  const int M = B * S;
  const float QS = 0.18033688011112042f;   // log2(e)/8

  char* w = (char*)d_ws;
  size_t off = 0;
  unsigned short* xb   = (unsigned short*)(w + off); off += (size_t)M * DM * 2;
  unsigned short* Wcat = (unsigned short*)(w + off); off += (size_t)3 * DM * DM * 2;
  unsigned short* Wob  = (unsigned short*)(w + off); off += (size_t)DM * DM * 2;
  unsigned short* QKVb = (unsigned short*)(w + off); off += (size_t)M * QLD * 2;
  unsigned short* Vtb  = (unsigned short*)(w + off); off += (size_t)M * DM * 2;
  float* tw  = (float*)(w + off); off += (size_t)S * 4;
  unsigned short* twb = (unsigned short*)(w + off); off += (size_t)S * 2;
  float* bcat = (float*)(w + off); off += (size_t)3 * DM * 4;
  unsigned short* Ob = xb;   // alias: xb dead after QKV gemm
  (void)ws_size; (void)n_in; (void)out_size;

  // fused prep (x conv, 4 weight convs, bias cat, tw) — one launch
  {
    int nx = M * DM / 4, nw = DM * DM / 4;
    int total = nx + 4 * nw;
    int tail = 3 * DM + S;
    int gridp = total / 256 + (tail + 255) / 256;
    k_prep<<<gridp, 256, 0, stream>>>(x, Wq, Wk, Wv, Wo, bq, bk, bv, coords,
                                      xb, Wcat, Wob, bcat, tw, twb, M, S, QS);
  }

  // fused QKV projection: [M,1024] x [3072,1024]^T -> [M,3072]
  gemm_bt<0><<<(M / BM) * (3 * DM / BN), 256, 0, stream>>>(xb, Wcat, bcat, QKVb, M, 3 * DM, DM, QLD);

  // V transpose (+ tw prescale, kappa permute) + attention
  k_transpose<<<B * NHEAD * (S / 64), 256, 0, stream>>>(QKVb + 2 * DM, tw, Vtb, S, QLD);
  k_attn<<<B * NHEAD * (S / 128), 256, 0, stream>>>(QKVb, Vtb, twb, Ob, S);

  // output projection (f32 out)
  gemm_bt<1><<<(M / BM) * (DM / BN), 256, 0, stream>>>(Ob, Wob, bo, d_out, M, DM, DM, DM);
}

// Round 13
// 111.065 us; speedup vs baseline: 1.4782x; 1.0187x over previous
//
#include <hip/hip_runtime.h>

#define DM 1024
#define NHEAD 16
#define DK 64
#define QLD 3072   // fused QKV row stride

typedef short bf16x8 __attribute__((ext_vector_type(8)));
typedef float f32x4 __attribute__((ext_vector_type(4)));

__device__ __forceinline__ unsigned short f2bf(float f) {
  union { float f; unsigned u; } v; v.f = f;
  return (unsigned short)((v.u + 0x7fffu + ((v.u >> 16) & 1u)) >> 16);
}
__device__ __forceinline__ float bf2f(unsigned short h) {
  union { unsigned u; float f; } v; v.u = ((unsigned)h) << 16; return v.f;
}
__device__ __forceinline__ float fexp2(float x) {   // bare v_exp_f32: args bounded, no fixup needed
  float r; asm("v_exp_f32 %0, %1" : "=v"(r) : "v"(x)); return r;
}

__device__ __forceinline__ void gld16(const void* g, void* l) {
  __builtin_amdgcn_global_load_lds((const __attribute__((address_space(1))) void*)g,
                                   (__attribute__((address_space(3))) void*)l, 16, 0, 0);
}

// kappa: key = K(slot) within each 64-tile; bijective. Matches swapped-QK register layout.
__device__ __forceinline__ int kappa(int p) {
  return (p & 32) + (((p & 7) >> 2) << 4) + (((p >> 3) & 3) << 2) + (p & 3);
}

// ---------------- fused prep: x conv + 4 weight convs + bias cat + tw ----------------
__global__ void k_prep(const float* __restrict__ x, const float* __restrict__ Wq,
                       const float* __restrict__ Wk, const float* __restrict__ Wv,
                       const float* __restrict__ Wo, const float* __restrict__ bq,
                       const float* __restrict__ bk, const float* __restrict__ bv,
                       const float* __restrict__ coords,
                       unsigned short* __restrict__ xb, unsigned short* __restrict__ Wcat,
                       unsigned short* __restrict__ Wob, float* __restrict__ bcat,
                       float* __restrict__ tw, unsigned short* __restrict__ twb,
                       int M, int S, float QS) {
  const int nx = M * DM / 4;       // x float4 count
  const int nw = DM * DM / 4;      // per-weight float4 count
  const int total = nx + 4 * nw;
  int gid = blockIdx.x * 256 + threadIdx.x;

  auto conv4 = [&](const float* src, unsigned short* dst, int idx, float sc) {
    float4 v = *(const float4*)(src + idx * 4);
    ushort4 o;
    o.x = f2bf(v.x * sc); o.y = f2bf(v.y * sc);
    o.z = f2bf(v.z * sc); o.w = f2bf(v.w * sc);
    *(ushort4*)(dst + idx * 4) = o;
  };

  if (gid < nx) { conv4(x, xb, gid, 1.0f); return; }
  if (gid < nx + nw) { conv4(Wq, Wcat, gid - nx, QS); return; }
  if (gid < nx + 2 * nw) { conv4(Wk, Wcat + DM * DM, gid - nx - nw, 1.0f); return; }
  if (gid < nx + 3 * nw) { conv4(Wv, Wcat + 2 * DM * DM, gid - nx - 2 * nw, 1.0f); return; }
  if (gid < total) { conv4(Wo, Wob, gid - nx - 3 * nw, 1.0f); return; }

  int r = gid - total;
  if (r < 3 * DM) {
    float v = (r < DM) ? bq[r] * QS : (r < 2 * DM ? bk[r - DM] : bv[r - 2 * DM]);
    bcat[r] = v;
    return;
  }
  r -= 3 * DM;
  if (r < S) {
    auto twval = [&](int k) {
      float a = (k > 0)     ? fabsf(coords[k] - coords[k - 1]) : 0.f;
      float b = (k < S - 1) ? fabsf(coords[k + 1] - coords[k]) : 0.f;
      return 0.5f * (a + b);
    };
    tw[r] = twval(r);
    int key = (r & ~63) + kappa(r & 63);
    twb[r] = f2bf(twval(key));
  }
}

// ---------------- GEMM: C[M,N] = A[M,K] * B[N,K]^T + bias ----------------
// T2 XOR-swizzled LDS; bf16 path stores C via LDS restage for coalescing.
// VFUSE: blocks covering the V feature range write transposed/tw-scaled/kappa-permuted
// Vt tiles directly (and skip the C store) — replaces the k_transpose kernel.
#define BM 128
#define BN 128
#define BKK 64

template<int OUTF32, int VFUSE>
__global__ __launch_bounds__(256)
void gemm_bt(const unsigned short* __restrict__ A, const unsigned short* __restrict__ B,
             const float* __restrict__ bias, void* __restrict__ C,
             int M, int N, int K, int ldc,
             const float* __restrict__ twp, unsigned short* __restrict__ Vt, int S) {
  __shared__ __align__(16) unsigned short smem[4][BM * BKK];   // [0..1]=A dbuf, [2..3]=B dbuf
  const int tid = threadIdx.x;
  const int lane = tid & 63;
  const int wid = tid >> 6;
  const int rr = lane & 15, g = lane >> 4;
  const int nbn = N / BN;
  const int cpx = gridDim.x >> 3;
  const int bid = ((gridDim.x & 7) == 0) ? (blockIdx.x & 7) * cpx + (blockIdx.x >> 3)
                                         : blockIdx.x;
  const int bm = bid / nbn, bn = bid % nbn;
  const int wr = wid >> 1, wc = wid & 1;
  const int nkt = K / BKK;

  const unsigned short* Abase = A + (size_t)bm * BM * K;
  const unsigned short* Bbase = B + (size_t)bn * BN * K;

  auto stage = [&](int buf, int kt) {
#pragma unroll
    for (int j = 0; j < 4; ++j) {
      int o = j * 256 + tid;
      int row = o >> 3;
      int cb = ((o & 7) * 16) ^ ((row & 7) << 4);   // inverse-swizzled source byte col
      gld16((const char*)(Abase + (size_t)row * K + kt * BKK) + cb, &smem[buf][o * 8]);
      gld16((const char*)(Bbase + (size_t)row * K + kt * BKK) + cb, &smem[2 + buf][o * 8]);
    }
  };

  f32x4 acc[4][4] = {};
  stage(0, 0);
  int cur = 0;
  const int sw = (rr & 7) << 4;
  for (int kt = 0; kt < nkt; ++kt) {
    __syncthreads();
    if (kt + 1 < nkt) stage(cur ^ 1, kt + 1);
    const char* a0 = (const char*)&smem[cur][(wr * 64) * BKK];
    const char* b0 = (const char*)&smem[2 + cur][(wc * 64) * BKK];
#pragma unroll
    for (int kk = 0; kk < 2; ++kk) {
      const int co = (kk * 64 + g * 16);
      bf16x8 af[4], bfr[4];
#pragma unroll
      for (int m = 0; m < 4; ++m)
        af[m] = *(const bf16x8*)(a0 + (m * 16 + rr) * 128 + (co ^ sw));
#pragma unroll
      for (int n = 0; n < 4; ++n)
        bfr[n] = *(const bf16x8*)(b0 + (n * 16 + rr) * 128 + (co ^ sw));
      __builtin_amdgcn_s_setprio(1);
#pragma unroll
      for (int m = 0; m < 4; ++m)
#pragma unroll
        for (int n = 0; n < 4; ++n)
          acc[m][n] = __builtin_amdgcn_mfma_f32_16x16x32_bf16(af[m], bfr[n], acc[m][n], 0, 0, 0);
      __builtin_amdgcn_s_setprio(0);
    }
    cur ^= 1;
  }

  const int crow0 = bm * BM + wr * 64;
  const int ccol0 = bn * BN + wc * 64;
  if (OUTF32) {
#pragma unroll
    for (int n = 0; n < 4; ++n) {
      const int col = ccol0 + n * 16 + rr;
      const float bn_ = bias ? bias[col] : 0.f;
#pragma unroll
      for (int m = 0; m < 4; ++m)
#pragma unroll
        for (int r = 0; r < 4; ++r) {
          const int row = crow0 + m * 16 + g * 4 + r;
          ((float*)C)[(size_t)row * ldc + col] = acc[m][n][r] + bn_;
        }
    }
  } else {
    // restage through LDS (row pad 136 shorts)
    unsigned short* L = &smem[0][0];   // 128*136 = 17408 shorts <= 32768
    __syncthreads();                   // all fragment reads of smem done
#pragma unroll
    for (int n = 0; n < 4; ++n) {
      const float bn_ = bias ? bias[ccol0 + n * 16 + rr] : 0.f;
#pragma unroll
      for (int m = 0; m < 4; ++m)
#pragma unroll
        for (int r = 0; r < 4; ++r)
          L[(wr * 64 + m * 16 + g * 4 + r) * 136 + wc * 64 + n * 16 + rr] =
              f2bf(acc[m][n][r] + bn_);
    }
    __syncthreads();
    if (VFUSE && bn >= (2 * DM) / BN) {
      // ---- fused V-transpose epilogue: Vt[bh][d][s] with tw prescale + kappa permute ----
      const int tilesPerB = S / BM;
      const int bb = bm / tilesPerB;
      const int s0 = (bm % tilesPerB) * BM;
      const int vcol0 = bn * BN - 2 * DM;        // first V feature col of this tile
      const int hh = tid >> 7;                   // head-half within tile (0/1)
      const int dd = (tid >> 1) & 63;            // d within head
      const int stl = tid & 1;                   // which 64-s subtile
      const int head = (vcol0 >> 6) + hh;
      const int lcol = hh * 64 + dd;
      unsigned short* vdst = Vt + ((size_t)(bb * NHEAD + head) * DK + dd) * S + s0 + stl * 64;
      const float* twg = twp + s0 + stl * 64;
      unsigned short tmp[8];
#pragma unroll
      for (int j8 = 0; j8 < 8; ++j8) {
#pragma unroll
        for (int j = 0; j < 8; ++j) {
          const int kl = kappa(j8 * 8 + j);
          tmp[j] = f2bf(bf2f(L[(stl * 64 + kl) * 136 + lcol]) * twg[kl]);
        }
        *(uint4*)&vdst[j8 * 8] = *(const uint4*)&tmp[0];
      }
    } else {
      unsigned short* Cb = (unsigned short*)C + (size_t)(bm * BM) * ldc + bn * BN;
#pragma unroll
      for (int i = 0; i < 8; ++i) {
        int o = i * 256 + tid;
        int row = o >> 4;
        int cc = (o & 15) * 8;
        uint4 v = *(const uint4*)&L[row * 136 + cc];
        *(uint4*)&Cb[(size_t)row * ldc + cc] = v;
      }
    }
  }
}

// ---------------- attention: swapped QK^T, P in registers, KVBLK=128 (R9 schedule) ----------------
// 4 waves x 32 q-rows = 128 q-rows per block; 128-key staged tiles, two 64-key halves.
__global__ __launch_bounds__(256)
void k_attn(const unsigned short* __restrict__ QKV, const unsigned short* __restrict__ Vt,
            const unsigned short* __restrict__ twb, unsigned short* __restrict__ O, int S) {
  __shared__ __align__(16) unsigned short sK[2][128 * 64];   // 128 keys x 64 d
  __shared__ __align__(16) unsigned short sV[2][64 * 128];   // 64 d x 128 key-slots
  const int tid = threadIdx.x, lane = tid & 63, wid = tid >> 6;
  const int rr = lane & 15, g = lane >> 4;
  const int nqt = S / 128;
  const int cpx = gridDim.x >> 3;
  const int swz = (blockIdx.x & 7) * cpx + (blockIdx.x >> 3);
  const int qt = swz % nqt;
  const int bh = swz / nqt;
  const int h = bh & (NHEAD - 1), b = bh / NHEAD;

  const unsigned short* Qbase = QKV + ((size_t)b * S + qt * 128 + wid * 32) * QLD + h * DK;
  const unsigned short* Kbase = QKV + (size_t)b * S * QLD + DM + h * DK;
  const unsigned short* Vbase = Vt + (size_t)bh * DK * S;

  bf16x8 aq[2][2];
#pragma unroll
  for (int qm = 0; qm < 2; ++qm) {
    aq[qm][0] = *(const bf16x8*)&Qbase[(size_t)(qm * 16 + rr) * QLD + g * 8];
    aq[qm][1] = *(const bf16x8*)&Qbase[(size_t)(qm * 16 + rr) * QLD + 32 + g * 8];
  }

  f32x4 acc[2][5] = {};
  const f32x4 z0 = {};

  auto stage = [&](int buf, int kt) {
    // K: 128 rows x 128B, 1024 chunks
#pragma unroll
    for (int j = 0; j < 4; ++j) {
      int o = j * 256 + tid;
      int row = o >> 3;
      int cb = ((o & 7) * 16) ^ ((row & 7) << 4);
      gld16((const char*)(Kbase + (size_t)(kt * 128 + row) * QLD) + cb, &sK[buf][o * 8]);
    }
    // V: 64 rows x 256B, 1024 chunks (swizzle within each 128B half-row)
#pragma unroll
    for (int j = 0; j < 4; ++j) {
      int o = j * 256 + tid;
      int row = o >> 4;
      int cb = ((o & 15) * 16) ^ ((row & 7) << 4);
      gld16((const char*)(Vbase + (size_t)row * S + kt * 128) + cb, &sV[buf][o * 8]);
    }
  };

  stage(0, 0);
  int cur = 0;
  const int nkt = S / 128;
  for (int kt = 0; kt < nkt; ++kt) {
    __syncthreads();
    if (kt + 1 < nkt) stage(cur ^ 1, kt + 1);

#pragma unroll
    for (int half = 0; half < 2; ++half) {
      // swapped scores for this 64-key half: s[qm][f] = P[key=16f+4g+r][q=qm*16+rr]
      f32x4 s[2][4];
#pragma unroll
      for (int f = 0; f < 4; ++f) {
        const int row = half * 64 + f * 16 + rr;
        const int swr = (rr & 7) << 4;   // row&7 == rr&7
        bf16x8 kA0 = *(const bf16x8*)((const char*)&sK[cur][row * 64] + ((g * 16) ^ swr));
        bf16x8 kA1 = *(const bf16x8*)((const char*)&sK[cur][row * 64] + ((64 + g * 16) ^ swr));
        __builtin_amdgcn_s_setprio(1);
#pragma unroll
        for (int qm = 0; qm < 2; ++qm) {
          f32x4 z = __builtin_amdgcn_mfma_f32_16x16x32_bf16(kA0, aq[qm][0], z0, 0, 0, 0);
          s[qm][f] = __builtin_amdgcn_mfma_f32_16x16x32_bf16(kA1, aq[qm][1], z, 0, 0, 0);
        }
        __builtin_amdgcn_s_setprio(0);
      }

      // p = exp2(s) in place (lane-local)
#pragma unroll
      for (int qm = 0; qm < 2; ++qm)
#pragma unroll
        for (int f = 0; f < 4; ++f)
#pragma unroll
          for (int r = 0; r < 4; ++r)
            s[qm][f][r] = fexp2(s[qm][f][r]);

      // pack P into A-frags in registers: slot kk*32+g*8+j -> (f=2kk+(j>>2), r=j&3)
      bf16x8 pa[2][2];
#pragma unroll
      for (int qm = 0; qm < 2; ++qm)
#pragma unroll
        for (int kk = 0; kk < 2; ++kk) {
          union { bf16x8 v; unsigned u[4]; } pk;
          asm("v_cvt_pk_bf16_f32 %0, %1, %2" : "=v"(pk.u[0]) : "v"(s[qm][2*kk][0]),   "v"(s[qm][2*kk][1]));
          asm("v_cvt_pk_bf16_f32 %0, %1, %2" : "=v"(pk.u[1]) : "v"(s[qm][2*kk][2]),   "v"(s[qm][2*kk][3]));
          asm("v_cvt_pk_bf16_f32 %0, %1, %2" : "=v"(pk.u[2]) : "v"(s[qm][2*kk+1][0]), "v"(s[qm][2*kk+1][1]));
          asm("v_cvt_pk_bf16_f32 %0, %1, %2" : "=v"(pk.u[3]) : "v"(s[qm][2*kk+1][2]), "v"(s[qm][2*kk+1][3]));
          pa[qm][kk] = pk.v;
        }

      // tw fragments for denominator (kappa-ordered, per 64-subtile)
      bf16x8 tw0 = *(const bf16x8*)&twb[kt * 128 + half * 64 + g * 8];
      bf16x8 tw1 = *(const bf16x8*)&twb[kt * 128 + half * 64 + 32 + g * 8];

      // PV + denominator: V frags reused across both q-subtiles
#pragma unroll
      for (int kk = 0; kk < 2; ++kk) {
        __builtin_amdgcn_s_setprio(1);
#pragma unroll
        for (int n = 0; n < 4; ++n) {
          const int vrow = n * 16 + rr;
          const int cb = (half * 128 + kk * 64 + g * 16) ^ ((vrow & 7) << 4);
          bf16x8 bv = *(const bf16x8*)((const char*)&sV[cur][vrow * 128] + cb);
#pragma unroll
          for (int qm = 0; qm < 2; ++qm)
            acc[qm][n] = __builtin_amdgcn_mfma_f32_16x16x32_bf16(pa[qm][kk], bv, acc[qm][n], 0, 0, 0);
        }
#pragma unroll
        for (int qm = 0; qm < 2; ++qm)
          acc[qm][4] = __builtin_amdgcn_mfma_f32_16x16x32_bf16(pa[qm][kk], kk ? tw1 : tw0, acc[qm][4], 0, 0, 0);
        __builtin_amdgcn_s_setprio(0);
      }
    }
    cur ^= 1;
  }

  unsigned short* Ob = O + ((size_t)b * S + qt * 128 + wid * 32) * DM + h * DK;
#pragma unroll
  for (int qm = 0; qm < 2; ++qm)
#pragma unroll
    for (int n = 0; n < 4; ++n)
#pragma unroll
      for (int r = 0; r < 4; ++r) {
        const int q = qm * 16 + g * 4 + r;
        const int d = n * 16 + rr;
        Ob[(size_t)q * DM + d] = f2bf(acc[qm][n][r] / acc[qm][4][r]);
      }
}

// ---------------- launch ----------------
extern "C" void kernel_launch(void* const* d_in, const int* in_sizes, int n_in,
                              void* d_out, int out_size, void* d_ws, size_t ws_size,
                              hipStream_t stream) {
  const float* x      = (const float*)d_in[0];
  const float* coords = (const float*)d_in[1];
  const float* Wq = (const float*)d_in[2];
  const float* bq = (const float*)d_in[3];
  const float* Wk = (const float*)d_in[4];
  const float* bk = (const float*)d_in[5];
  const float* Wv = (const float*)d_in[6];
  const float* bv = (const float*)d_in[7];
  const float* Wo = (const float*)d_in[8];
  const float* bo = (const float*)d_in[9];

  const int S = in_sizes[1];
  const int B = in_sizes[0] / (S * DM);
  const int M = B * S;
  const float QS = 0.18033688011112042f;   // log2(e)/8

  char* w = (char*)d_ws;
  size_t off = 0;
  unsigned short* xb   = (unsigned short*)(w + off); off += (size_t)M * DM * 2;
  unsigned short* Wcat = (unsigned short*)(w + off); off += (size_t)3 * DM * DM * 2;
  unsigned short* Wob  = (unsigned short*)(w + off); off += (size_t)DM * DM * 2;
  unsigned short* QKVb = (unsigned short*)(w + off); off += (size_t)M * QLD * 2;
  unsigned short* Vtb  = (unsigned short*)(w + off); off += (size_t)M * DM * 2;
  float* tw  = (float*)(w + off); off += (size_t)S * 4;
  unsigned short* twb = (unsigned short*)(w + off); off += (size_t)S * 2;
  float* bcat = (float*)(w + off); off += (size_t)3 * DM * 4;
  unsigned short* Ob = xb;   // alias: xb dead after QKV gemm
  (void)ws_size; (void)n_in; (void)out_size;

  // fused prep (x conv, 4 weight convs, bias cat, tw) — one launch
  {
    int nx = M * DM / 4, nw = DM * DM / 4;
    int total = nx + 4 * nw;
    int tail = 3 * DM + S;
    int gridp = total / 256 + (tail + 255) / 256;
    k_prep<<<gridp, 256, 0, stream>>>(x, Wq, Wk, Wv, Wo, bq, bk, bv, coords,
                                      xb, Wcat, Wob, bcat, tw, twb, M, S, QS);
  }

  // fused QKV projection: [M,1024] x [3072,1024]^T -> [M,3072]
  // V-range blocks write Vt directly (transpose + tw + kappa) — no k_transpose kernel.
  gemm_bt<0, 1><<<(M / BM) * (3 * DM / BN), 256, 0, stream>>>(
      xb, Wcat, bcat, QKVb, M, 3 * DM, DM, QLD, tw, Vtb, S);

  // attention
  k_attn<<<B * NHEAD * (S / 128), 256, 0, stream>>>(QKVb, Vtb, twb, Ob, S);

  // output projection (f32 out)
  gemm_bt<1, 0><<<(M / BM) * (DM / BN), 256, 0, stream>>>(
      Ob, Wob, bo, d_out, M, DM, DM, DM, nullptr, nullptr, S);
}

// Round 14
// 109.387 us; speedup vs baseline: 1.5009x; 1.0153x over previous
//
#include <hip/hip_runtime.h>

#define DM 1024
#define NHEAD 16
#define DK 64
#define QLD 3072   // fused QKV row stride

typedef short bf16x8 __attribute__((ext_vector_type(8)));
typedef float f32x4 __attribute__((ext_vector_type(4)));

__device__ __forceinline__ unsigned short f2bf(float f) {
  union { float f; unsigned u; } v; v.f = f;
  return (unsigned short)((v.u + 0x7fffu + ((v.u >> 16) & 1u)) >> 16);
}
__device__ __forceinline__ float bf2f(unsigned short h) {
  union { unsigned u; float f; } v; v.u = ((unsigned)h) << 16; return v.f;
}
__device__ __forceinline__ float fexp2(float x) {   // bare v_exp_f32: args bounded, no fixup needed
  float r; asm("v_exp_f32 %0, %1" : "=v"(r) : "v"(x)); return r;
}

__device__ __forceinline__ void gld16(const void* g, void* l) {
  __builtin_amdgcn_global_load_lds((const __attribute__((address_space(1))) void*)g,
                                   (__attribute__((address_space(3))) void*)l, 16, 0, 0);
}

// kappa: key = K(slot) within each 64-tile; bijective. Matches swapped-QK register layout.
__device__ __forceinline__ int kappa(int p) {
  return (p & 32) + (((p & 7) >> 2) << 4) + (((p >> 3) & 3) << 2) + (p & 3);
}

// ---------------- fused prep: x conv + 4 weight convs + bias cat + tw ----------------
__global__ void k_prep(const float* __restrict__ x, const float* __restrict__ Wq,
                       const float* __restrict__ Wk, const float* __restrict__ Wv,
                       const float* __restrict__ Wo, const float* __restrict__ bq,
                       const float* __restrict__ bk, const float* __restrict__ bv,
                       const float* __restrict__ coords,
                       unsigned short* __restrict__ xb, unsigned short* __restrict__ Wcat,
                       unsigned short* __restrict__ Wob, float* __restrict__ bcat,
                       float* __restrict__ tw, unsigned short* __restrict__ twb,
                       int M, int S, float QS) {
  const int nx = M * DM / 4;       // x float4 count
  const int nw = DM * DM / 4;      // per-weight float4 count
  const int total = nx + 4 * nw;
  int gid = blockIdx.x * 256 + threadIdx.x;

  auto conv4 = [&](const float* src, unsigned short* dst, int idx, float sc) {
    float4 v = *(const float4*)(src + idx * 4);
    ushort4 o;
    o.x = f2bf(v.x * sc); o.y = f2bf(v.y * sc);
    o.z = f2bf(v.z * sc); o.w = f2bf(v.w * sc);
    *(ushort4*)(dst + idx * 4) = o;
  };

  if (gid < nx) { conv4(x, xb, gid, 1.0f); return; }
  if (gid < nx + nw) { conv4(Wq, Wcat, gid - nx, QS); return; }
  if (gid < nx + 2 * nw) { conv4(Wk, Wcat + DM * DM, gid - nx - nw, 1.0f); return; }
  if (gid < nx + 3 * nw) { conv4(Wv, Wcat + 2 * DM * DM, gid - nx - 2 * nw, 1.0f); return; }
  if (gid < total) { conv4(Wo, Wob, gid - nx - 3 * nw, 1.0f); return; }

  int r = gid - total;
  if (r < 3 * DM) {
    float v = (r < DM) ? bq[r] * QS : (r < 2 * DM ? bk[r - DM] : bv[r - 2 * DM]);
    bcat[r] = v;
    return;
  }
  r -= 3 * DM;
  if (r < S) {
    auto twval = [&](int k) {
      float a = (k > 0)     ? fabsf(coords[k] - coords[k - 1]) : 0.f;
      float b = (k < S - 1) ? fabsf(coords[k + 1] - coords[k]) : 0.f;
      return 0.5f * (a + b);
    };
    tw[r] = twval(r);
    int key = (r & ~63) + kappa(r & 63);
    twb[r] = f2bf(twval(key));
  }
}

// ---------------- GEMM: C[M,N] = A[M,K] * B[N,K]^T + bias (bf16 out) ----------------
// T2 XOR-swizzled LDS; C stored via LDS restage for coalescing.
// VFUSE: blocks covering the V feature range write transposed/tw-scaled/kappa-permuted
// Vt tiles directly (and skip the C store) — replaces the k_transpose kernel.
#define BM 128
#define BN 128
#define BKK 64

template<int VFUSE>
__global__ __launch_bounds__(256)
void gemm_bt(const unsigned short* __restrict__ A, const unsigned short* __restrict__ B,
             const float* __restrict__ bias, void* __restrict__ C,
             int M, int N, int K, int ldc,
             const float* __restrict__ twp, unsigned short* __restrict__ Vt, int S) {
  __shared__ __align__(16) unsigned short smem[4][BM * BKK];   // [0..1]=A dbuf, [2..3]=B dbuf
  const int tid = threadIdx.x;
  const int lane = tid & 63;
  const int wid = tid >> 6;
  const int rr = lane & 15, g = lane >> 4;
  const int nbn = N / BN;
  const int cpx = gridDim.x >> 3;
  const int bid = ((gridDim.x & 7) == 0) ? (blockIdx.x & 7) * cpx + (blockIdx.x >> 3)
                                         : blockIdx.x;
  const int bm = bid / nbn, bn = bid % nbn;
  const int wr = wid >> 1, wc = wid & 1;
  const int nkt = K / BKK;

  const unsigned short* Abase = A + (size_t)bm * BM * K;
  const unsigned short* Bbase = B + (size_t)bn * BN * K;

  auto stage = [&](int buf, int kt) {
#pragma unroll
    for (int j = 0; j < 4; ++j) {
      int o = j * 256 + tid;
      int row = o >> 3;
      int cb = ((o & 7) * 16) ^ ((row & 7) << 4);   // inverse-swizzled source byte col
      gld16((const char*)(Abase + (size_t)row * K + kt * BKK) + cb, &smem[buf][o * 8]);
      gld16((const char*)(Bbase + (size_t)row * K + kt * BKK) + cb, &smem[2 + buf][o * 8]);
    }
  };

  f32x4 acc[4][4] = {};
  stage(0, 0);
  int cur = 0;
  const int sw = (rr & 7) << 4;
  for (int kt = 0; kt < nkt; ++kt) {
    __syncthreads();
    if (kt + 1 < nkt) stage(cur ^ 1, kt + 1);
    const char* a0 = (const char*)&smem[cur][0];
    const char* b0 = (const char*)&smem[2 + cur][0];
#pragma unroll
    for (int kk = 0; kk < 2; ++kk) {
      const int co = (kk * 64 + g * 16);
      bf16x8 af[4], bfr[4];
#pragma unroll
      for (int m = 0; m < 4; ++m)
        af[m] = *(const bf16x8*)(a0 + (wr * 64 + m * 16 + rr) * 128 + (co ^ sw));
#pragma unroll
      for (int n = 0; n < 4; ++n)
        bfr[n] = *(const bf16x8*)(b0 + (wc * 64 + n * 16 + rr) * 128 + (co ^ sw));
      __builtin_amdgcn_s_setprio(1);
#pragma unroll
      for (int m = 0; m < 4; ++m)
#pragma unroll
        for (int n = 0; n < 4; ++n)
          acc[m][n] = __builtin_amdgcn_mfma_f32_16x16x32_bf16(af[m], bfr[n], acc[m][n], 0, 0, 0);
      __builtin_amdgcn_s_setprio(0);
    }
    cur ^= 1;
  }

  const int ccol0 = bn * BN + wc * 64;
  // restage through LDS (row pad 136 shorts)
  unsigned short* L = &smem[0][0];   // 128*136 = 17408 shorts <= 32768
  __syncthreads();                   // all fragment reads of smem done
#pragma unroll
  for (int n = 0; n < 4; ++n) {
    const float bn_ = bias ? bias[ccol0 + n * 16 + rr] : 0.f;
#pragma unroll
    for (int m = 0; m < 4; ++m)
#pragma unroll
      for (int r = 0; r < 4; ++r)
        L[(wr * 64 + m * 16 + g * 4 + r) * 136 + wc * 64 + n * 16 + rr] =
            f2bf(acc[m][n][r] + bn_);
  }
  __syncthreads();
  if (VFUSE && bn >= (2 * DM) / BN) {
    // ---- fused V-transpose epilogue: Vt[bh][d][s] with tw prescale + kappa permute ----
    const int tilesPerB = S / BM;
    const int bb = bm / tilesPerB;
    const int s0 = (bm % tilesPerB) * BM;
    const int vcol0 = bn * BN - 2 * DM;        // first V feature col of this tile
    const int hh = tid >> 7;                   // head-half within tile (0/1)
    const int dd = (tid >> 1) & 63;            // d within head
    const int stl = tid & 1;                   // which 64-s subtile
    const int head = (vcol0 >> 6) + hh;
    const int lcol = hh * 64 + dd;
    unsigned short* vdst = Vt + ((size_t)(bb * NHEAD + head) * DK + dd) * S + s0 + stl * 64;
    const float* twg = twp + s0 + stl * 64;
    unsigned short tmp[8];
#pragma unroll
    for (int j8 = 0; j8 < 8; ++j8) {
#pragma unroll
      for (int j = 0; j < 8; ++j) {
        const int kl = kappa(j8 * 8 + j);
        tmp[j] = f2bf(bf2f(L[(stl * 64 + kl) * 136 + lcol]) * twg[kl]);
      }
      *(uint4*)&vdst[j8 * 8] = *(const uint4*)&tmp[0];
    }
  } else {
    unsigned short* Cb = (unsigned short*)C + (size_t)(bm * BM) * ldc + bn * BN;
#pragma unroll
    for (int i = 0; i < 8; ++i) {
      int o = i * 256 + tid;
      int row = o >> 4;
      int cc = (o & 15) * 8;
      uint4 v = *(const uint4*)&L[row * 136 + cc];
      *(uint4*)&Cb[(size_t)row * ldc + cc] = v;
    }
  }
}

// ---------------- Wo GEMM: C[M,N] f32 = A[M,K]*B[N,K]^T + bias; BM=64 x BN=128 tile ----------------
// 512 blocks (2/CU). 2x2 wave grid, per-wave 32x64. f32 LDS-restaged coalesced store.
#define WBM 64
__global__ __launch_bounds__(256)
void gemm_wo(const unsigned short* __restrict__ A, const unsigned short* __restrict__ B,
             const float* __restrict__ bias, float* __restrict__ C,
             int M, int N, int K, int ldc) {
  __shared__ __align__(16) unsigned short smem[6][WBM * BKK];  // [0..1]=A dbuf(16KB), [2..5]=B dbuf(32KB)
  const int tid = threadIdx.x;
  const int lane = tid & 63;
  const int wid = tid >> 6;
  const int rr = lane & 15, g = lane >> 4;
  const int nbn = N / BN;                       // 8
  const int cpx = gridDim.x >> 3;
  const int bid = (blockIdx.x & 7) * cpx + (blockIdx.x >> 3);   // grid 512 % 8 == 0
  const int bm = bid / nbn, bn = bid % nbn;
  const int wr = wid >> 1, wc = wid & 1;
  const int nkt = K / BKK;

  const unsigned short* Abase = A + (size_t)bm * WBM * K;
  const unsigned short* Bbase = B + (size_t)bn * BN * K;

  auto stage = [&](int buf, int kt) {
    {   // A: 64 rows x 128B = 512 chunks -> 2/thread
#pragma unroll
      for (int j = 0; j < 2; ++j) {
        int o = j * 256 + tid;
        int row = o >> 3;
        int cb = ((o & 7) * 16) ^ ((row & 7) << 4);
        gld16((const char*)(Abase + (size_t)row * K + kt * BKK) + cb, &smem[buf][o * 8]);
      }
    }
    {   // B: 128 rows x 128B = 1024 chunks -> 4/thread
#pragma unroll
      for (int j = 0; j < 4; ++j) {
        int o = j * 256 + tid;
        int row = o >> 3;
        int cb = ((o & 7) * 16) ^ ((row & 7) << 4);
        gld16((const char*)(Bbase + (size_t)row * K + kt * BKK) + cb, &smem[2 + buf * 2][o * 8]);
      }
    }
  };

  f32x4 acc[2][4] = {};
  stage(0, 0);
  int cur = 0;
  const int sw = (rr & 7) << 4;
  for (int kt = 0; kt < nkt; ++kt) {
    __syncthreads();
    if (kt + 1 < nkt) stage(cur ^ 1, kt + 1);
    const char* a0 = (const char*)&smem[cur][0];
    const char* b0 = (const char*)&smem[2 + cur * 2][0];
#pragma unroll
    for (int kk = 0; kk < 2; ++kk) {
      const int co = (kk * 64 + g * 16);
      bf16x8 af[2], bfr[4];
#pragma unroll
      for (int m = 0; m < 2; ++m)
        af[m] = *(const bf16x8*)(a0 + (wr * 32 + m * 16 + rr) * 128 + (co ^ sw));
#pragma unroll
      for (int n = 0; n < 4; ++n)
        bfr[n] = *(const bf16x8*)(b0 + (wc * 64 + n * 16 + rr) * 128 + (co ^ sw));
      __builtin_amdgcn_s_setprio(1);
#pragma unroll
      for (int m = 0; m < 2; ++m)
#pragma unroll
        for (int n = 0; n < 4; ++n)
          acc[m][n] = __builtin_amdgcn_mfma_f32_16x16x32_bf16(af[m], bfr[n], acc[m][n], 0, 0, 0);
      __builtin_amdgcn_s_setprio(0);
    }
    cur ^= 1;
  }

  // f32 restage: 64 rows x 132 f32 (pad 4 -> banks shift 4/row), 33.8KB within 48KB smem
  float* Lf = (float*)&smem[0][0];
  __syncthreads();
#pragma unroll
  for (int n = 0; n < 4; ++n) {
    const float bn_ = bias[bn * BN + wc * 64 + n * 16 + rr];
#pragma unroll
    for (int m = 0; m < 2; ++m)
#pragma unroll
      for (int r = 0; r < 4; ++r)
        Lf[(wr * 32 + m * 16 + g * 4 + r) * 132 + wc * 64 + n * 16 + rr] =
            acc[m][n][r] + bn_;
  }
  __syncthreads();
  float* Cb = C + (size_t)(bm * WBM) * ldc + bn * BN;
#pragma unroll
  for (int i = 0; i < 8; ++i) {
    int o = i * 256 + tid;         // 2048 uint4 chunks: 64 rows x 32 chunks
    int row = o >> 5;
    int cc = (o & 31) * 4;
    float4 v = *(const float4*)&Lf[row * 132 + cc];
    *(float4*)&Cb[(size_t)row * ldc + cc] = v;
  }
}

// ---------------- attention: swapped QK^T, P in registers, KVBLK=128 (R9 schedule) ----------------
// 4 waves x 32 q-rows = 128 q-rows per block; 128-key staged tiles, two 64-key halves.
__global__ __launch_bounds__(256)
void k_attn(const unsigned short* __restrict__ QKV, const unsigned short* __restrict__ Vt,
            const unsigned short* __restrict__ twb, unsigned short* __restrict__ O, int S) {
  __shared__ __align__(16) unsigned short sK[2][128 * 64];   // 128 keys x 64 d
  __shared__ __align__(16) unsigned short sV[2][64 * 128];   // 64 d x 128 key-slots
  const int tid = threadIdx.x, lane = tid & 63, wid = tid >> 6;
  const int rr = lane & 15, g = lane >> 4;
  const int nqt = S / 128;
  const int cpx = gridDim.x >> 3;
  const int swz = (blockIdx.x & 7) * cpx + (blockIdx.x >> 3);
  const int qt = swz % nqt;
  const int bh = swz / nqt;
  const int h = bh & (NHEAD - 1), b = bh / NHEAD;

  const unsigned short* Qbase = QKV + ((size_t)b * S + qt * 128 + wid * 32) * QLD + h * DK;
  const unsigned short* Kbase = QKV + (size_t)b * S * QLD + DM + h * DK;
  const unsigned short* Vbase = Vt + (size_t)bh * DK * S;

  bf16x8 aq[2][2];
#pragma unroll
  for (int qm = 0; qm < 2; ++qm) {
    aq[qm][0] = *(const bf16x8*)&Qbase[(size_t)(qm * 16 + rr) * QLD + g * 8];
    aq[qm][1] = *(const bf16x8*)&Qbase[(size_t)(qm * 16 + rr) * QLD + 32 + g * 8];
  }

  f32x4 acc[2][5] = {};
  const f32x4 z0 = {};

  auto stage = [&](int buf, int kt) {
    // K: 128 rows x 128B, 1024 chunks
#pragma unroll
    for (int j = 0; j < 4; ++j) {
      int o = j * 256 + tid;
      int row = o >> 3;
      int cb = ((o & 7) * 16) ^ ((row & 7) << 4);
      gld16((const char*)(Kbase + (size_t)(kt * 128 + row) * QLD) + cb, &sK[buf][o * 8]);
    }
    // V: 64 rows x 256B, 1024 chunks (swizzle within each 128B half-row)
#pragma unroll
    for (int j = 0; j < 4; ++j) {
      int o = j * 256 + tid;
      int row = o >> 4;
      int cb = ((o & 15) * 16) ^ ((row & 7) << 4);
      gld16((const char*)(Vbase + (size_t)row * S + kt * 128) + cb, &sV[buf][o * 8]);
    }
  };

  stage(0, 0);
  int cur = 0;
  const int nkt = S / 128;
  for (int kt = 0; kt < nkt; ++kt) {
    __syncthreads();
    if (kt + 1 < nkt) stage(cur ^ 1, kt + 1);

#pragma unroll
    for (int half = 0; half < 2; ++half) {
      // swapped scores for this 64-key half: s[qm][f] = P[key=16f+4g+r][q=qm*16+rr]
      f32x4 s[2][4];
#pragma unroll
      for (int f = 0; f < 4; ++f) {
        const int row = half * 64 + f * 16 + rr;
        const int swr = (rr & 7) << 4;   // row&7 == rr&7
        bf16x8 kA0 = *(const bf16x8*)((const char*)&sK[cur][row * 64] + ((g * 16) ^ swr));
        bf16x8 kA1 = *(const bf16x8*)((const char*)&sK[cur][row * 64] + ((64 + g * 16) ^ swr));
        __builtin_amdgcn_s_setprio(1);
#pragma unroll
        for (int qm = 0; qm < 2; ++qm) {
          f32x4 z = __builtin_amdgcn_mfma_f32_16x16x32_bf16(kA0, aq[qm][0], z0, 0, 0, 0);
          s[qm][f] = __builtin_amdgcn_mfma_f32_16x16x32_bf16(kA1, aq[qm][1], z, 0, 0, 0);
        }
        __builtin_amdgcn_s_setprio(0);
      }

      // p = exp2(s) in place (lane-local)
#pragma unroll
      for (int qm = 0; qm < 2; ++qm)
#pragma unroll
        for (int f = 0; f < 4; ++f)
#pragma unroll
          for (int r = 0; r < 4; ++r)
            s[qm][f][r] = fexp2(s[qm][f][r]);

      // pack P into A-frags in registers: slot kk*32+g*8+j -> (f=2kk+(j>>2), r=j&3)
      bf16x8 pa[2][2];
#pragma unroll
      for (int qm = 0; qm < 2; ++qm)
#pragma unroll
        for (int kk = 0; kk < 2; ++kk) {
          union { bf16x8 v; unsigned u[4]; } pk;
          asm("v_cvt_pk_bf16_f32 %0, %1, %2" : "=v"(pk.u[0]) : "v"(s[qm][2*kk][0]),   "v"(s[qm][2*kk][1]));
          asm("v_cvt_pk_bf16_f32 %0, %1, %2" : "=v"(pk.u[1]) : "v"(s[qm][2*kk][2]),   "v"(s[qm][2*kk][3]));
          asm("v_cvt_pk_bf16_f32 %0, %1, %2" : "=v"(pk.u[2]) : "v"(s[qm][2*kk+1][0]), "v"(s[qm][2*kk+1][1]));
          asm("v_cvt_pk_bf16_f32 %0, %1, %2" : "=v"(pk.u[3]) : "v"(s[qm][2*kk+1][2]), "v"(s[qm][2*kk+1][3]));
          pa[qm][kk] = pk.v;
        }

      // tw fragments for denominator (kappa-ordered, per 64-subtile)
      bf16x8 tw0 = *(const bf16x8*)&twb[kt * 128 + half * 64 + g * 8];
      bf16x8 tw1 = *(const bf16x8*)&twb[kt * 128 + half * 64 + 32 + g * 8];

      // PV + denominator: V frags reused across both q-subtiles
#pragma unroll
      for (int kk = 0; kk < 2; ++kk) {
        __builtin_amdgcn_s_setprio(1);
#pragma unroll
        for (int n = 0; n < 4; ++n) {
          const int vrow = n * 16 + rr;
          const int cb = (half * 128 + kk * 64 + g * 16) ^ ((vrow & 7) << 4);
          bf16x8 bv = *(const bf16x8*)((const char*)&sV[cur][vrow * 128] + cb);
#pragma unroll
          for (int qm = 0; qm < 2; ++qm)
            acc[qm][n] = __builtin_amdgcn_mfma_f32_16x16x32_bf16(pa[qm][kk], bv, acc[qm][n], 0, 0, 0);
        }
#pragma unroll
        for (int qm = 0; qm < 2; ++qm)
          acc[qm][4] = __builtin_amdgcn_mfma_f32_16x16x32_bf16(pa[qm][kk], kk ? tw1 : tw0, acc[qm][4], 0, 0, 0);
        __builtin_amdgcn_s_setprio(0);
      }
    }
    cur ^= 1;
  }

  unsigned short* Ob = O + ((size_t)b * S + qt * 128 + wid * 32) * DM + h * DK;
#pragma unroll
  for (int qm = 0; qm < 2; ++qm)
#pragma unroll
    for (int n = 0; n < 4; ++n)
#pragma unroll
      for (int r = 0; r < 4; ++r) {
        const int q = qm * 16 + g * 4 + r;
        const int d = n * 16 + rr;
        Ob[(size_t)q * DM + d] = f2bf(acc[qm][n][r] / acc[qm][4][r]);
      }
}

// ---------------- launch ----------------
extern "C" void kernel_launch(void* const* d_in, const int* in_sizes, int n_in,
                              void* d_out, int out_size, void* d_ws, size_t ws_size,
                              hipStream_t stream) {
  const float* x      = (const float*)d_in[0];
  const float* coords = (const float*)d_in[1];
  const float* Wq = (const float*)d_in[2];
  const float* bq = (const float*)d_in[3];
  const float* Wk = (const float*)d_in[4];
  const float* bk = (const float*)d_in[5];
  const float* Wv = (const float*)d_in[6];
  const float* bv = (const float*)d_in[7];
  const float* Wo = (const float*)d_in[8];
  const float* bo = (const float*)d_in[9];

  const int S = in_sizes[1];
  const int B = in_sizes[0] / (S * DM);
  const int M = B * S;
  const float QS = 0.18033688011112042f;   // log2(e)/8

  char* w = (char*)d_ws;
  size_t off = 0;
  unsigned short* xb   = (unsigned short*)(w + off); off += (size_t)M * DM * 2;
  unsigned short* Wcat = (unsigned short*)(w + off); off += (size_t)3 * DM * DM * 2;
  unsigned short* Wob  = (unsigned short*)(w + off); off += (size_t)DM * DM * 2;
  unsigned short* QKVb = (unsigned short*)(w + off); off += (size_t)M * QLD * 2;
  unsigned short* Vtb  = (unsigned short*)(w + off); off += (size_t)M * DM * 2;
  float* tw  = (float*)(w + off); off += (size_t)S * 4;
  unsigned short* twb = (unsigned short*)(w + off); off += (size_t)S * 2;
  float* bcat = (float*)(w + off); off += (size_t)3 * DM * 4;
  unsigned short* Ob = xb;   // alias: xb dead after QKV gemm
  (void)ws_size; (void)n_in; (void)out_size;

  // fused prep (x conv, 4 weight convs, bias cat, tw) — one launch
  {
    int nx = M * DM / 4, nw = DM * DM / 4;
    int total = nx + 4 * nw;
    int tail = 3 * DM + S;
    int gridp = total / 256 + (tail + 255) / 256;
    k_prep<<<gridp, 256, 0, stream>>>(x, Wq, Wk, Wv, Wo, bq, bk, bv, coords,
                                      xb, Wcat, Wob, bcat, tw, twb, M, S, QS);
  }

  // fused QKV projection: [M,1024] x [3072,1024]^T -> [M,3072]
  // V-range blocks write Vt directly (transpose + tw + kappa) — no k_transpose kernel.
  gemm_bt<1><<<(M / BM) * (3 * DM / BN), 256, 0, stream>>>(
      xb, Wcat, bcat, QKVb, M, 3 * DM, DM, QLD, tw, Vtb, S);

  // attention
  k_attn<<<B * NHEAD * (S / 128), 256, 0, stream>>>(QKVb, Vtb, twb, Ob, S);

  // output projection (f32 out, 64x128 tile, 512 blocks)
  gemm_wo<<<(M / WBM) * (DM / BN), 256, 0, stream>>>(Ob, Wob, bo, (float*)d_out, M, DM, DM, DM);
}

// Round 15
// 107.479 us; speedup vs baseline: 1.5276x; 1.0177x over previous
//
#include <hip/hip_runtime.h>

#define DM 1024
#define NHEAD 16
#define DK 64
#define QLD 3072   // fused QKV row stride

typedef short bf16x8 __attribute__((ext_vector_type(8)));
typedef float f32x4 __attribute__((ext_vector_type(4)));

__device__ __forceinline__ unsigned short f2bf(float f) {
  union { float f; unsigned u; } v; v.f = f;
  return (unsigned short)((v.u + 0x7fffu + ((v.u >> 16) & 1u)) >> 16);
}
__device__ __forceinline__ float bf2f(unsigned short h) {
  union { unsigned u; float f; } v; v.u = ((unsigned)h) << 16; return v.f;
}
__device__ __forceinline__ float fexp2(float x) {   // bare v_exp_f32: args bounded, no fixup needed
  float r; asm("v_exp_f32 %0, %1" : "=v"(r) : "v"(x)); return r;
}

__device__ __forceinline__ void gld16(const void* g, void* l) {
  __builtin_amdgcn_global_load_lds((const __attribute__((address_space(1))) void*)g,
                                   (__attribute__((address_space(3))) void*)l, 16, 0, 0);
}

// kappa: key = K(slot) within each 64-tile; bijective. Matches swapped-QK register layout.
__device__ __forceinline__ int kappa(int p) {
  return (p & 32) + (((p & 7) >> 2) << 4) + (((p >> 3) & 3) << 2) + (p & 3);
}

// ---------------- fused prep: x conv + 4 weight convs + bias cat + tw ----------------
__global__ void k_prep(const float* __restrict__ x, const float* __restrict__ Wq,
                       const float* __restrict__ Wk, const float* __restrict__ Wv,
                       const float* __restrict__ Wo, const float* __restrict__ bq,
                       const float* __restrict__ bk, const float* __restrict__ bv,
                       const float* __restrict__ coords,
                       unsigned short* __restrict__ xb, unsigned short* __restrict__ Wcat,
                       unsigned short* __restrict__ Wob, float* __restrict__ bcat,
                       float* __restrict__ tw, unsigned short* __restrict__ twb,
                       int M, int S, float QS) {
  const int nx = M * DM / 4;       // x float4 count
  const int nw = DM * DM / 4;      // per-weight float4 count
  const int total = nx + 4 * nw;
  int gid = blockIdx.x * 256 + threadIdx.x;

  auto conv4 = [&](const float* src, unsigned short* dst, int idx, float sc) {
    float4 v = *(const float4*)(src + idx * 4);
    ushort4 o;
    o.x = f2bf(v.x * sc); o.y = f2bf(v.y * sc);
    o.z = f2bf(v.z * sc); o.w = f2bf(v.w * sc);
    *(ushort4*)(dst + idx * 4) = o;
  };

  if (gid < nx) { conv4(x, xb, gid, 1.0f); return; }
  if (gid < nx + nw) { conv4(Wq, Wcat, gid - nx, QS); return; }
  if (gid < nx + 2 * nw) { conv4(Wk, Wcat + DM * DM, gid - nx - nw, 1.0f); return; }
  if (gid < nx + 3 * nw) { conv4(Wv, Wcat + 2 * DM * DM, gid - nx - 2 * nw, 1.0f); return; }
  if (gid < total) { conv4(Wo, Wob, gid - nx - 3 * nw, 1.0f); return; }

  int r = gid - total;
  if (r < 3 * DM) {
    float v = (r < DM) ? bq[r] * QS : (r < 2 * DM ? bk[r - DM] : bv[r - 2 * DM]);
    bcat[r] = v;
    return;
  }
  r -= 3 * DM;
  if (r < S) {
    auto twval = [&](int k) {
      float a = (k > 0)     ? fabsf(coords[k] - coords[k - 1]) : 0.f;
      float b = (k < S - 1) ? fabsf(coords[k + 1] - coords[k]) : 0.f;
      return 0.5f * (a + b);
    };
    tw[r] = twval(r);
    int key = (r & ~63) + kappa(r & 63);
    twb[r] = f2bf(twval(key));
  }
}

// ---------------- GEMM: C[M,N] = A[M,K] * B[N,K]^T + bias (bf16 out) ----------------
// T2 XOR-swizzled LDS; C stored via LDS restage for coalescing.
// VFUSE: blocks covering the V feature range write transposed/tw-scaled/kappa-permuted
// Vt tiles directly (and skip the C store) — replaces the k_transpose kernel.
#define BM 128
#define BN 128
#define BKK 64

template<int VFUSE>
__global__ __launch_bounds__(256)
void gemm_bt(const unsigned short* __restrict__ A, const unsigned short* __restrict__ B,
             const float* __restrict__ bias, void* __restrict__ C,
             int M, int N, int K, int ldc,
             const float* __restrict__ twp, unsigned short* __restrict__ Vt, int S) {
  __shared__ __align__(16) unsigned short smem[4][BM * BKK];   // [0..1]=A dbuf, [2..3]=B dbuf
  const int tid = threadIdx.x;
  const int lane = tid & 63;
  const int wid = tid >> 6;
  const int rr = lane & 15, g = lane >> 4;
  const int nbn = N / BN;
  const int cpx = gridDim.x >> 3;
  const int bid = ((gridDim.x & 7) == 0) ? (blockIdx.x & 7) * cpx + (blockIdx.x >> 3)
                                         : blockIdx.x;
  const int bm = bid / nbn, bn = bid % nbn;
  const int wr = wid >> 1, wc = wid & 1;
  const int nkt = K / BKK;

  const unsigned short* Abase = A + (size_t)bm * BM * K;
  const unsigned short* Bbase = B + (size_t)bn * BN * K;

  auto stage = [&](int buf, int kt) {
#pragma unroll
    for (int j = 0; j < 4; ++j) {
      int o = j * 256 + tid;
      int row = o >> 3;
      int cb = ((o & 7) * 16) ^ ((row & 7) << 4);   // inverse-swizzled source byte col
      gld16((const char*)(Abase + (size_t)row * K + kt * BKK) + cb, &smem[buf][o * 8]);
      gld16((const char*)(Bbase + (size_t)row * K + kt * BKK) + cb, &smem[2 + buf][o * 8]);
    }
  };

  f32x4 acc[4][4] = {};
  stage(0, 0);
  int cur = 0;
  const int sw = (rr & 7) << 4;
  for (int kt = 0; kt < nkt; ++kt) {
    __syncthreads();
    if (kt + 1 < nkt) stage(cur ^ 1, kt + 1);
    const char* a0 = (const char*)&smem[cur][0];
    const char* b0 = (const char*)&smem[2 + cur][0];
#pragma unroll
    for (int kk = 0; kk < 2; ++kk) {
      const int co = (kk * 64 + g * 16);
      bf16x8 af[4], bfr[4];
#pragma unroll
      for (int m = 0; m < 4; ++m)
        af[m] = *(const bf16x8*)(a0 + (wr * 64 + m * 16 + rr) * 128 + (co ^ sw));
#pragma unroll
      for (int n = 0; n < 4; ++n)
        bfr[n] = *(const bf16x8*)(b0 + (wc * 64 + n * 16 + rr) * 128 + (co ^ sw));
      __builtin_amdgcn_s_setprio(1);
#pragma unroll
      for (int m = 0; m < 4; ++m)
#pragma unroll
        for (int n = 0; n < 4; ++n)
          acc[m][n] = __builtin_amdgcn_mfma_f32_16x16x32_bf16(af[m], bfr[n], acc[m][n], 0, 0, 0);
      __builtin_amdgcn_s_setprio(0);
    }
    cur ^= 1;
  }

  const int ccol0 = bn * BN + wc * 64;
  // restage through LDS (row pad 136 shorts)
  unsigned short* L = &smem[0][0];   // 128*136 = 17408 shorts <= 32768
  __syncthreads();                   // all fragment reads of smem done
#pragma unroll
  for (int n = 0; n < 4; ++n) {
    const float bn_ = bias ? bias[ccol0 + n * 16 + rr] : 0.f;
#pragma unroll
    for (int m = 0; m < 4; ++m)
#pragma unroll
      for (int r = 0; r < 4; ++r)
        L[(wr * 64 + m * 16 + g * 4 + r) * 136 + wc * 64 + n * 16 + rr] =
            f2bf(acc[m][n][r] + bn_);
  }
  __syncthreads();
  if (VFUSE && bn >= (2 * DM) / BN) {
    // ---- fused V-transpose epilogue: Vt[bh][d][s] with tw prescale + kappa permute ----
    const int tilesPerB = S / BM;
    const int bb = bm / tilesPerB;
    const int s0 = (bm % tilesPerB) * BM;
    const int vcol0 = bn * BN - 2 * DM;        // first V feature col of this tile
    const int hh = tid >> 7;                   // head-half within tile (0/1)
    const int dd = (tid >> 1) & 63;            // d within head
    const int stl = tid & 1;                   // which 64-s subtile
    const int head = (vcol0 >> 6) + hh;
    const int lcol = hh * 64 + dd;
    unsigned short* vdst = Vt + ((size_t)(bb * NHEAD + head) * DK + dd) * S + s0 + stl * 64;
    const float* twg = twp + s0 + stl * 64;
    unsigned short tmp[8];
#pragma unroll
    for (int j8 = 0; j8 < 8; ++j8) {
#pragma unroll
      for (int j = 0; j < 8; ++j) {
        const int kl = kappa(j8 * 8 + j);
        tmp[j] = f2bf(bf2f(L[(stl * 64 + kl) * 136 + lcol]) * twg[kl]);
      }
      *(uint4*)&vdst[j8 * 8] = *(const uint4*)&tmp[0];
    }
  } else {
    unsigned short* Cb = (unsigned short*)C + (size_t)(bm * BM) * ldc + bn * BN;
#pragma unroll
    for (int i = 0; i < 8; ++i) {
      int o = i * 256 + tid;
      int row = o >> 4;
      int cc = (o & 15) * 8;
      uint4 v = *(const uint4*)&L[row * 136 + cc];
      *(uint4*)&Cb[(size_t)row * ldc + cc] = v;
    }
  }
}

// ---------------- Wo GEMM: C[M,N] f32 = A[M,K]*B[N,K]^T + bias; BM=64 x BN=128 tile ----------------
// 512 blocks (2/CU). 2x2 wave grid, per-wave 32x64. f32 LDS-restaged coalesced store.
#define WBM 64
__global__ __launch_bounds__(256)
void gemm_wo(const unsigned short* __restrict__ A, const unsigned short* __restrict__ B,
             const float* __restrict__ bias, float* __restrict__ C,
             int M, int N, int K, int ldc) {
  __shared__ __align__(16) unsigned short smem[6][WBM * BKK];  // [0..1]=A dbuf(16KB), [2..5]=B dbuf(32KB)
  const int tid = threadIdx.x;
  const int lane = tid & 63;
  const int wid = tid >> 6;
  const int rr = lane & 15, g = lane >> 4;
  const int nbn = N / BN;                       // 8
  const int cpx = gridDim.x >> 3;
  const int bid = (blockIdx.x & 7) * cpx + (blockIdx.x >> 3);   // grid 512 % 8 == 0
  const int bm = bid / nbn, bn = bid % nbn;
  const int wr = wid >> 1, wc = wid & 1;
  const int nkt = K / BKK;

  const unsigned short* Abase = A + (size_t)bm * WBM * K;
  const unsigned short* Bbase = B + (size_t)bn * BN * K;

  auto stage = [&](int buf, int kt) {
    {   // A: 64 rows x 128B = 512 chunks -> 2/thread
#pragma unroll
      for (int j = 0; j < 2; ++j) {
        int o = j * 256 + tid;
        int row = o >> 3;
        int cb = ((o & 7) * 16) ^ ((row & 7) << 4);
        gld16((const char*)(Abase + (size_t)row * K + kt * BKK) + cb, &smem[buf][o * 8]);
      }
    }
    {   // B: 128 rows x 128B = 1024 chunks -> 4/thread
#pragma unroll
      for (int j = 0; j < 4; ++j) {
        int o = j * 256 + tid;
        int row = o >> 3;
        int cb = ((o & 7) * 16) ^ ((row & 7) << 4);
        gld16((const char*)(Bbase + (size_t)row * K + kt * BKK) + cb, &smem[2 + buf * 2][o * 8]);
      }
    }
  };

  f32x4 acc[2][4] = {};
  stage(0, 0);
  int cur = 0;
  const int sw = (rr & 7) << 4;
  for (int kt = 0; kt < nkt; ++kt) {
    __syncthreads();
    if (kt + 1 < nkt) stage(cur ^ 1, kt + 1);
    const char* a0 = (const char*)&smem[cur][0];
    const char* b0 = (const char*)&smem[2 + cur * 2][0];
#pragma unroll
    for (int kk = 0; kk < 2; ++kk) {
      const int co = (kk * 64 + g * 16);
      bf16x8 af[2], bfr[4];
#pragma unroll
      for (int m = 0; m < 2; ++m)
        af[m] = *(const bf16x8*)(a0 + (wr * 32 + m * 16 + rr) * 128 + (co ^ sw));
#pragma unroll
      for (int n = 0; n < 4; ++n)
        bfr[n] = *(const bf16x8*)(b0 + (wc * 64 + n * 16 + rr) * 128 + (co ^ sw));
      __builtin_amdgcn_s_setprio(1);
#pragma unroll
      for (int m = 0; m < 2; ++m)
#pragma unroll
        for (int n = 0; n < 4; ++n)
          acc[m][n] = __builtin_amdgcn_mfma_f32_16x16x32_bf16(af[m], bfr[n], acc[m][n], 0, 0, 0);
      __builtin_amdgcn_s_setprio(0);
    }
    cur ^= 1;
  }

  // f32 restage: 64 rows x 132 f32 (pad 4 -> banks shift 4/row), 33.8KB within 48KB smem
  float* Lf = (float*)&smem[0][0];
  __syncthreads();
#pragma unroll
  for (int n = 0; n < 4; ++n) {
    const float bn_ = bias[bn * BN + wc * 64 + n * 16 + rr];
#pragma unroll
    for (int m = 0; m < 2; ++m)
#pragma unroll
      for (int r = 0; r < 4; ++r)
        Lf[(wr * 32 + m * 16 + g * 4 + r) * 132 + wc * 64 + n * 16 + rr] =
            acc[m][n][r] + bn_;
  }
  __syncthreads();
  float* Cb = C + (size_t)(bm * WBM) * ldc + bn * BN;
#pragma unroll
  for (int i = 0; i < 8; ++i) {
    int o = i * 256 + tid;         // 2048 uint4 chunks: 64 rows x 32 chunks
    int row = o >> 5;
    int cc = (o & 31) * 4;
    float4 v = *(const float4*)&Lf[row * 132 + cc];
    *(float4*)&Cb[(size_t)row * ldc + cc] = v;
  }
}

// ---------------- attention: swapped QK^T, P in registers, KVBLK=128 ----------------
// 4 waves x 32 q-rows = 128 q-rows per block; 128-key staged tiles, two 64-key halves.
// V-frag + tw loads hoisted to half-top so PV/denom never stall on LDS/global latency.
__global__ __launch_bounds__(256)
void k_attn(const unsigned short* __restrict__ QKV, const unsigned short* __restrict__ Vt,
            const unsigned short* __restrict__ twb, unsigned short* __restrict__ O, int S) {
  __shared__ __align__(16) unsigned short sK[2][128 * 64];   // 128 keys x 64 d
  __shared__ __align__(16) unsigned short sV[2][64 * 128];   // 64 d x 128 key-slots
  const int tid = threadIdx.x, lane = tid & 63, wid = tid >> 6;
  const int rr = lane & 15, g = lane >> 4;
  const int nqt = S / 128;
  const int cpx = gridDim.x >> 3;
  const int swz = (blockIdx.x & 7) * cpx + (blockIdx.x >> 3);
  const int qt = swz % nqt;
  const int bh = swz / nqt;
  const int h = bh & (NHEAD - 1), b = bh / NHEAD;

  const unsigned short* Qbase = QKV + ((size_t)b * S + qt * 128 + wid * 32) * QLD + h * DK;
  const unsigned short* Kbase = QKV + (size_t)b * S * QLD + DM + h * DK;
  const unsigned short* Vbase = Vt + (size_t)bh * DK * S;

  bf16x8 aq[2][2];
#pragma unroll
  for (int qm = 0; qm < 2; ++qm) {
    aq[qm][0] = *(const bf16x8*)&Qbase[(size_t)(qm * 16 + rr) * QLD + g * 8];
    aq[qm][1] = *(const bf16x8*)&Qbase[(size_t)(qm * 16 + rr) * QLD + 32 + g * 8];
  }

  f32x4 acc[2][5] = {};
  const f32x4 z0 = {};

  auto stage = [&](int buf, int kt) {
    // K: 128 rows x 128B, 1024 chunks
#pragma unroll
    for (int j = 0; j < 4; ++j) {
      int o = j * 256 + tid;
      int row = o >> 3;
      int cb = ((o & 7) * 16) ^ ((row & 7) << 4);
      gld16((const char*)(Kbase + (size_t)(kt * 128 + row) * QLD) + cb, &sK[buf][o * 8]);
    }
    // V: 64 rows x 256B, 1024 chunks (swizzle within each 128B half-row)
#pragma unroll
    for (int j = 0; j < 4; ++j) {
      int o = j * 256 + tid;
      int row = o >> 4;
      int cb = ((o & 15) * 16) ^ ((row & 7) << 4);
      gld16((const char*)(Vbase + (size_t)row * S + kt * 128) + cb, &sV[buf][o * 8]);
    }
  };

  stage(0, 0);
  int cur = 0;
  const int nkt = S / 128;
  const int swr = (rr & 7) << 4;   // row&7 == rr&7 for all frag rows
  for (int kt = 0; kt < nkt; ++kt) {
    __syncthreads();
    if (kt + 1 < nkt) stage(cur ^ 1, kt + 1);

#pragma unroll
    for (int half = 0; half < 2; ++half) {
      // ---- hoisted loads: K frags, V frags, tw frags all issued up front ----
      bf16x8 kA[4][2];
#pragma unroll
      for (int f = 0; f < 4; ++f) {
        const int row = half * 64 + f * 16 + rr;
        kA[f][0] = *(const bf16x8*)((const char*)&sK[cur][row * 64] + ((g * 16) ^ swr));
        kA[f][1] = *(const bf16x8*)((const char*)&sK[cur][row * 64] + ((64 + g * 16) ^ swr));
      }
      bf16x8 vB[2][4];
#pragma unroll
      for (int kk = 0; kk < 2; ++kk)
#pragma unroll
        for (int n = 0; n < 4; ++n) {
          const int vrow = n * 16 + rr;
          const int cb = (half * 128 + kk * 64 + g * 16) ^ ((vrow & 7) << 4);
          vB[kk][n] = *(const bf16x8*)((const char*)&sV[cur][vrow * 128] + cb);
        }
      bf16x8 tw0 = *(const bf16x8*)&twb[kt * 128 + half * 64 + g * 8];
      bf16x8 tw1 = *(const bf16x8*)&twb[kt * 128 + half * 64 + 32 + g * 8];

      // ---- swapped scores: s[qm][f] = P[key=16f+4g+r][q=qm*16+rr] ----
      f32x4 s[2][4];
      __builtin_amdgcn_s_setprio(1);
#pragma unroll
      for (int f = 0; f < 4; ++f)
#pragma unroll
        for (int qm = 0; qm < 2; ++qm) {
          f32x4 z = __builtin_amdgcn_mfma_f32_16x16x32_bf16(kA[f][0], aq[qm][0], z0, 0, 0, 0);
          s[qm][f] = __builtin_amdgcn_mfma_f32_16x16x32_bf16(kA[f][1], aq[qm][1], z, 0, 0, 0);
        }
      __builtin_amdgcn_s_setprio(0);

      // ---- p = exp2(s) in place (lane-local) ----
#pragma unroll
      for (int qm = 0; qm < 2; ++qm)
#pragma unroll
        for (int f = 0; f < 4; ++f)
#pragma unroll
          for (int r = 0; r < 4; ++r)
            s[qm][f][r] = fexp2(s[qm][f][r]);

      // ---- pack P into A-frags: slot kk*32+g*8+j -> (f=2kk+(j>>2), r=j&3) ----
      bf16x8 pa[2][2];
#pragma unroll
      for (int qm = 0; qm < 2; ++qm)
#pragma unroll
        for (int kk = 0; kk < 2; ++kk) {
          union { bf16x8 v; unsigned u[4]; } pk;
          asm("v_cvt_pk_bf16_f32 %0, %1, %2" : "=v"(pk.u[0]) : "v"(s[qm][2*kk][0]),   "v"(s[qm][2*kk][1]));
          asm("v_cvt_pk_bf16_f32 %0, %1, %2" : "=v"(pk.u[1]) : "v"(s[qm][2*kk][2]),   "v"(s[qm][2*kk][3]));
          asm("v_cvt_pk_bf16_f32 %0, %1, %2" : "=v"(pk.u[2]) : "v"(s[qm][2*kk+1][0]), "v"(s[qm][2*kk+1][1]));
          asm("v_cvt_pk_bf16_f32 %0, %1, %2" : "=v"(pk.u[3]) : "v"(s[qm][2*kk+1][2]), "v"(s[qm][2*kk+1][3]));
          pa[qm][kk] = pk.v;
        }

      // ---- PV + denominator (V frags already in registers) ----
      __builtin_amdgcn_s_setprio(1);
#pragma unroll
      for (int kk = 0; kk < 2; ++kk) {
#pragma unroll
        for (int n = 0; n < 4; ++n)
#pragma unroll
          for (int qm = 0; qm < 2; ++qm)
            acc[qm][n] = __builtin_amdgcn_mfma_f32_16x16x32_bf16(pa[qm][kk], vB[kk][n], acc[qm][n], 0, 0, 0);
#pragma unroll
        for (int qm = 0; qm < 2; ++qm)
          acc[qm][4] = __builtin_amdgcn_mfma_f32_16x16x32_bf16(pa[qm][kk], kk ? tw1 : tw0, acc[qm][4], 0, 0, 0);
      }
      __builtin_amdgcn_s_setprio(0);
    }
    cur ^= 1;
  }

  unsigned short* Ob = O + ((size_t)b * S + qt * 128 + wid * 32) * DM + h * DK;
#pragma unroll
  for (int qm = 0; qm < 2; ++qm)
#pragma unroll
    for (int n = 0; n < 4; ++n)
#pragma unroll
      for (int r = 0; r < 4; ++r) {
        const int q = qm * 16 + g * 4 + r;
        const int d = n * 16 + rr;
        Ob[(size_t)q * DM + d] = f2bf(acc[qm][n][r] / acc[qm][4][r]);
      }
}

// ---------------- launch ----------------
extern "C" void kernel_launch(void* const* d_in, const int* in_sizes, int n_in,
                              void* d_out, int out_size, void* d_ws, size_t ws_size,
                              hipStream_t stream) {
  const float* x      = (const float*)d_in[0];
  const float* coords = (const float*)d_in[1];
  const float* Wq = (const float*)d_in[2];
  const float* bq = (const float*)d_in[3];
  const float* Wk = (const float*)d_in[4];
  const float* bk = (const float*)d_in[5];
  const float* Wv = (const float*)d_in[6];
  const float* bv = (const float*)d_in[7];
  const float* Wo = (const float*)d_in[8];
  const float* bo = (const float*)d_in[9];

  const int S = in_sizes[1];
  const int B = in_sizes[0] / (S * DM);
  const int M = B * S;
  const float QS = 0.18033688011112042f;   // log2(e)/8

  char* w = (char*)d_ws;
  size_t off = 0;
  unsigned short* xb   = (unsigned short*)(w + off); off += (size_t)M * DM * 2;
  unsigned short* Wcat = (unsigned short*)(w + off); off += (size_t)3 * DM * DM * 2;
  unsigned short* Wob  = (unsigned short*)(w + off); off += (size_t)DM * DM * 2;
  unsigned short* QKVb = (unsigned short*)(w + off); off += (size_t)M * QLD * 2;
  unsigned short* Vtb  = (unsigned short*)(w + off); off += (size_t)M * DM * 2;
  float* tw  = (float*)(w + off); off += (size_t)S * 4;
  unsigned short* twb = (unsigned short*)(w + off); off += (size_t)S * 2;
  float* bcat = (float*)(w + off); off += (size_t)3 * DM * 4;
  unsigned short* Ob = xb;   // alias: xb dead after QKV gemm
  (void)ws_size; (void)n_in; (void)out_size;

  // fused prep (x conv, 4 weight convs, bias cat, tw) — one launch
  {
    int nx = M * DM / 4, nw = DM * DM / 4;
    int total = nx + 4 * nw;
    int tail = 3 * DM + S;
    int gridp = total / 256 + (tail + 255) / 256;
    k_prep<<<gridp, 256, 0, stream>>>(x, Wq, Wk, Wv, Wo, bq, bk, bv, coords,
                                      xb, Wcat, Wob, bcat, tw, twb, M, S, QS);
  }

  // fused QKV projection: [M,1024] x [3072,1024]^T -> [M,3072]
  // V-range blocks write Vt directly (transpose + tw + kappa) — no k_transpose kernel.
  gemm_bt<1><<<(M / BM) * (3 * DM / BN), 256, 0, stream>>>(
      xb, Wcat, bcat, QKVb, M, 3 * DM, DM, QLD, tw, Vtb, S);

  // attention
  k_attn<<<B * NHEAD * (S / 128), 256, 0, stream>>>(QKVb, Vtb, twb, Ob, S);

  // output projection (f32 out, 64x128 tile, 512 blocks)
  gemm_wo<<<(M / WBM) * (DM / BN), 256, 0, stream>>>(Ob, Wob, bo, (float*)d_out, M, DM, DM, DM);
}

// Round 16
// 107.255 us; speedup vs baseline: 1.5308x; 1.0021x over previous
//
#include <hip/hip_runtime.h>

#define DM 1024
#define NHEAD 16
#define DK 64
#define QLD 3072   // fused QKV row stride

typedef short bf16x8 __attribute__((ext_vector_type(8)));
typedef float f32x4 __attribute__((ext_vector_type(4)));

__device__ __forceinline__ unsigned short f2bf(float f) {
  union { float f; unsigned u; } v; v.f = f;
  return (unsigned short)((v.u + 0x7fffu + ((v.u >> 16) & 1u)) >> 16);
}
__device__ __forceinline__ float bf2f(unsigned short h) {
  union { unsigned u; float f; } v; v.u = ((unsigned)h) << 16; return v.f;
}
__device__ __forceinline__ float fexp2(float x) {   // bare v_exp_f32: args bounded, no fixup needed
  float r; asm("v_exp_f32 %0, %1" : "=v"(r) : "v"(x)); return r;
}

__device__ __forceinline__ void gld16(const void* g, void* l) {
  __builtin_amdgcn_global_load_lds((const __attribute__((address_space(1))) void*)g,
                                   (__attribute__((address_space(3))) void*)l, 16, 0, 0);
}

// kappa: key = K(slot) within each 64-tile; bijective. Matches swapped-QK register layout.
__device__ __forceinline__ int kappa(int p) {
  return (p & 32) + (((p & 7) >> 2) << 4) + (((p >> 3) & 3) << 2) + (p & 3);
}

// ---------------- fused prep: x conv + 4 weight convs + bias cat + tw ----------------
__global__ void k_prep(const float* __restrict__ x, const float* __restrict__ Wq,
                       const float* __restrict__ Wk, const float* __restrict__ Wv,
                       const float* __restrict__ Wo, const float* __restrict__ bq,
                       const float* __restrict__ bk, const float* __restrict__ bv,
                       const float* __restrict__ coords,
                       unsigned short* __restrict__ xb, unsigned short* __restrict__ Wcat,
                       unsigned short* __restrict__ Wob, float* __restrict__ bcat,
                       float* __restrict__ tw, unsigned short* __restrict__ twb,
                       int M, int S, float QS) {
  const int nx = M * DM / 4;       // x float4 count
  const int nw = DM * DM / 4;      // per-weight float4 count
  const int total = nx + 4 * nw;
  int gid = blockIdx.x * 256 + threadIdx.x;

  auto conv4 = [&](const float* src, unsigned short* dst, int idx, float sc) {
    float4 v = *(const float4*)(src + idx * 4);
    ushort4 o;
    o.x = f2bf(v.x * sc); o.y = f2bf(v.y * sc);
    o.z = f2bf(v.z * sc); o.w = f2bf(v.w * sc);
    *(ushort4*)(dst + idx * 4) = o;
  };

  if (gid < nx) { conv4(x, xb, gid, 1.0f); return; }
  if (gid < nx + nw) { conv4(Wq, Wcat, gid - nx, QS); return; }
  if (gid < nx + 2 * nw) { conv4(Wk, Wcat + DM * DM, gid - nx - nw, 1.0f); return; }
  if (gid < nx + 3 * nw) { conv4(Wv, Wcat + 2 * DM * DM, gid - nx - 2 * nw, 1.0f); return; }
  if (gid < total) { conv4(Wo, Wob, gid - nx - 3 * nw, 1.0f); return; }

  int r = gid - total;
  if (r < 3 * DM) {
    float v = (r < DM) ? bq[r] * QS : (r < 2 * DM ? bk[r - DM] : bv[r - 2 * DM]);
    bcat[r] = v;
    return;
  }
  r -= 3 * DM;
  if (r < S) {
    auto twval = [&](int k) {
      float a = (k > 0)     ? fabsf(coords[k] - coords[k - 1]) : 0.f;
      float b = (k < S - 1) ? fabsf(coords[k + 1] - coords[k]) : 0.f;
      return 0.5f * (a + b);
    };
    tw[r] = twval(r);
    int key = (r & ~63) + kappa(r & 63);
    twb[r] = f2bf(twval(key));
  }
}

// ---------------- GEMM: C[M,N] = A[M,K] * B[N,K]^T + bias (bf16 out) ----------------
// T2 XOR-swizzled LDS; C stored via LDS restage for coalescing.
// VFUSE: blocks covering the V feature range write transposed/tw-scaled/kappa-permuted
// Vt tiles directly (and skip the C store) — replaces the k_transpose kernel.
#define BM 128
#define BN 128
#define BKK 64

template<int VFUSE>
__global__ __launch_bounds__(256)
void gemm_bt(const unsigned short* __restrict__ A, const unsigned short* __restrict__ B,
             const float* __restrict__ bias, void* __restrict__ C,
             int M, int N, int K, int ldc,
             const float* __restrict__ twp, unsigned short* __restrict__ Vt, int S) {
  __shared__ __align__(16) unsigned short smem[4][BM * BKK];   // [0..1]=A dbuf, [2..3]=B dbuf
  const int tid = threadIdx.x;
  const int lane = tid & 63;
  const int wid = tid >> 6;
  const int rr = lane & 15, g = lane >> 4;
  const int nbn = N / BN;
  const int cpx = gridDim.x >> 3;
  const int bid = ((gridDim.x & 7) == 0) ? (blockIdx.x & 7) * cpx + (blockIdx.x >> 3)
                                         : blockIdx.x;
  const int bm = bid / nbn, bn = bid % nbn;
  const int wr = wid >> 1, wc = wid & 1;
  const int nkt = K / BKK;

  const unsigned short* Abase = A + (size_t)bm * BM * K;
  const unsigned short* Bbase = B + (size_t)bn * BN * K;

  auto stage = [&](int buf, int kt) {
#pragma unroll
    for (int j = 0; j < 4; ++j) {
      int o = j * 256 + tid;
      int row = o >> 3;
      int cb = ((o & 7) * 16) ^ ((row & 7) << 4);   // inverse-swizzled source byte col
      gld16((const char*)(Abase + (size_t)row * K + kt * BKK) + cb, &smem[buf][o * 8]);
      gld16((const char*)(Bbase + (size_t)row * K + kt * BKK) + cb, &smem[2 + buf][o * 8]);
    }
  };

  f32x4 acc[4][4] = {};
  stage(0, 0);
  int cur = 0;
  const int sw = (rr & 7) << 4;
  for (int kt = 0; kt < nkt; ++kt) {
    __syncthreads();
    if (kt + 1 < nkt) stage(cur ^ 1, kt + 1);
    const char* a0 = (const char*)&smem[cur][0];
    const char* b0 = (const char*)&smem[2 + cur][0];
#pragma unroll
    for (int kk = 0; kk < 2; ++kk) {
      const int co = (kk * 64 + g * 16);
      bf16x8 af[4], bfr[4];
#pragma unroll
      for (int m = 0; m < 4; ++m)
        af[m] = *(const bf16x8*)(a0 + (wr * 64 + m * 16 + rr) * 128 + (co ^ sw));
#pragma unroll
      for (int n = 0; n < 4; ++n)
        bfr[n] = *(const bf16x8*)(b0 + (wc * 64 + n * 16 + rr) * 128 + (co ^ sw));
      __builtin_amdgcn_s_setprio(1);
#pragma unroll
      for (int m = 0; m < 4; ++m)
#pragma unroll
        for (int n = 0; n < 4; ++n)
          acc[m][n] = __builtin_amdgcn_mfma_f32_16x16x32_bf16(af[m], bfr[n], acc[m][n], 0, 0, 0);
      __builtin_amdgcn_s_setprio(0);
    }
    cur ^= 1;
  }

  const int ccol0 = bn * BN + wc * 64;
  // restage through LDS (row pad 136 shorts)
  unsigned short* L = &smem[0][0];   // 128*136 = 17408 shorts <= 32768
  __syncthreads();                   // all fragment reads of smem done
#pragma unroll
  for (int n = 0; n < 4; ++n) {
    const float bn_ = bias ? bias[ccol0 + n * 16 + rr] : 0.f;
#pragma unroll
    for (int m = 0; m < 4; ++m)
#pragma unroll
      for (int r = 0; r < 4; ++r)
        L[(wr * 64 + m * 16 + g * 4 + r) * 136 + wc * 64 + n * 16 + rr] =
            f2bf(acc[m][n][r] + bn_);
  }
  __syncthreads();
  if (VFUSE && bn >= (2 * DM) / BN) {
    // ---- fused V-transpose epilogue: Vt[bh][d][s] with tw prescale + kappa permute ----
    const int tilesPerB = S / BM;
    const int bb = bm / tilesPerB;
    const int s0 = (bm % tilesPerB) * BM;
    const int vcol0 = bn * BN - 2 * DM;        // first V feature col of this tile
    const int hh = tid >> 7;                   // head-half within tile (0/1)
    const int dd = (tid >> 1) & 63;            // d within head
    const int stl = tid & 1;                   // which 64-s subtile
    const int head = (vcol0 >> 6) + hh;
    const int lcol = hh * 64 + dd;
    unsigned short* vdst = Vt + ((size_t)(bb * NHEAD + head) * DK + dd) * S + s0 + stl * 64;
    const float* twg = twp + s0 + stl * 64;
    unsigned short tmp[8];
#pragma unroll
    for (int j8 = 0; j8 < 8; ++j8) {
#pragma unroll
      for (int j = 0; j < 8; ++j) {
        const int kl = kappa(j8 * 8 + j);
        tmp[j] = f2bf(bf2f(L[(stl * 64 + kl) * 136 + lcol]) * twg[kl]);
      }
      *(uint4*)&vdst[j8 * 8] = *(const uint4*)&tmp[0];
    }
  } else {
    unsigned short* Cb = (unsigned short*)C + (size_t)(bm * BM) * ldc + bn * BN;
#pragma unroll
    for (int i = 0; i < 8; ++i) {
      int o = i * 256 + tid;
      int row = o >> 4;
      int cc = (o & 15) * 8;
      uint4 v = *(const uint4*)&L[row * 136 + cc];
      *(uint4*)&Cb[(size_t)row * ldc + cc] = v;
    }
  }
}

// ---------------- Wo GEMM: C[M,N] f32 = A[M,K]*B[N,K]^T + bias; BM=64 x BN=128 tile ----------------
// 512 blocks (2/CU). 2x2 wave grid, per-wave 32x64. f32 LDS-restaged coalesced store.
#define WBM 64
__global__ __launch_bounds__(256)
void gemm_wo(const unsigned short* __restrict__ A, const unsigned short* __restrict__ B,
             const float* __restrict__ bias, float* __restrict__ C,
             int M, int N, int K, int ldc) {
  __shared__ __align__(16) unsigned short smem[6][WBM * BKK];  // [0..1]=A dbuf(16KB), [2..5]=B dbuf(32KB)
  const int tid = threadIdx.x;
  const int lane = tid & 63;
  const int wid = tid >> 6;
  const int rr = lane & 15, g = lane >> 4;
  const int nbn = N / BN;                       // 8
  const int cpx = gridDim.x >> 3;
  const int bid = (blockIdx.x & 7) * cpx + (blockIdx.x >> 3);   // grid 512 % 8 == 0
  const int bm = bid / nbn, bn = bid % nbn;
  const int wr = wid >> 1, wc = wid & 1;
  const int nkt = K / BKK;

  const unsigned short* Abase = A + (size_t)bm * WBM * K;
  const unsigned short* Bbase = B + (size_t)bn * BN * K;

  auto stage = [&](int buf, int kt) {
    {   // A: 64 rows x 128B = 512 chunks -> 2/thread
#pragma unroll
      for (int j = 0; j < 2; ++j) {
        int o = j * 256 + tid;
        int row = o >> 3;
        int cb = ((o & 7) * 16) ^ ((row & 7) << 4);
        gld16((const char*)(Abase + (size_t)row * K + kt * BKK) + cb, &smem[buf][o * 8]);
      }
    }
    {   // B: 128 rows x 128B = 1024 chunks -> 4/thread
#pragma unroll
      for (int j = 0; j < 4; ++j) {
        int o = j * 256 + tid;
        int row = o >> 3;
        int cb = ((o & 7) * 16) ^ ((row & 7) << 4);
        gld16((const char*)(Bbase + (size_t)row * K + kt * BKK) + cb, &smem[2 + buf * 2][o * 8]);
      }
    }
  };

  f32x4 acc[2][4] = {};
  stage(0, 0);
  int cur = 0;
  const int sw = (rr & 7) << 4;
  for (int kt = 0; kt < nkt; ++kt) {
    __syncthreads();
    if (kt + 1 < nkt) stage(cur ^ 1, kt + 1);
    const char* a0 = (const char*)&smem[cur][0];
    const char* b0 = (const char*)&smem[2 + cur * 2][0];
#pragma unroll
    for (int kk = 0; kk < 2; ++kk) {
      const int co = (kk * 64 + g * 16);
      bf16x8 af[2], bfr[4];
#pragma unroll
      for (int m = 0; m < 2; ++m)
        af[m] = *(const bf16x8*)(a0 + (wr * 32 + m * 16 + rr) * 128 + (co ^ sw));
#pragma unroll
      for (int n = 0; n < 4; ++n)
        bfr[n] = *(const bf16x8*)(b0 + (wc * 64 + n * 16 + rr) * 128 + (co ^ sw));
      __builtin_amdgcn_s_setprio(1);
#pragma unroll
      for (int m = 0; m < 2; ++m)
#pragma unroll
        for (int n = 0; n < 4; ++n)
          acc[m][n] = __builtin_amdgcn_mfma_f32_16x16x32_bf16(af[m], bfr[n], acc[m][n], 0, 0, 0);
      __builtin_amdgcn_s_setprio(0);
    }
    cur ^= 1;
  }

  // f32 restage: 64 rows x 132 f32 (pad 4 -> banks shift 4/row), 33.8KB within 48KB smem
  float* Lf = (float*)&smem[0][0];
  __syncthreads();
#pragma unroll
  for (int n = 0; n < 4; ++n) {
    const float bn_ = bias[bn * BN + wc * 64 + n * 16 + rr];
#pragma unroll
    for (int m = 0; m < 2; ++m)
#pragma unroll
      for (int r = 0; r < 4; ++r)
        Lf[(wr * 32 + m * 16 + g * 4 + r) * 132 + wc * 64 + n * 16 + rr] =
            acc[m][n][r] + bn_;
  }
  __syncthreads();
  float* Cb = C + (size_t)(bm * WBM) * ldc + bn * BN;
#pragma unroll
  for (int i = 0; i < 8; ++i) {
    int o = i * 256 + tid;         // 2048 uint4 chunks: 64 rows x 32 chunks
    int row = o >> 5;
    int cc = (o & 31) * 4;
    float4 v = *(const float4*)&Lf[row * 132 + cc];
    *(float4*)&Cb[(size_t)row * ldc + cc] = v;
  }
}

// ---------------- attention: swapped QK^T, P in registers, KVBLK=128 ----------------
// 4 waves x 32 q-rows = 128 q-rows per block; 128-key staged tiles, two 64-key halves.
// sV split per-half (128B rows) -> conflict-free V reads; coalesced epilogue via LDS restage.
__global__ __launch_bounds__(256)
void k_attn(const unsigned short* __restrict__ QKV, const unsigned short* __restrict__ Vt,
            const unsigned short* __restrict__ twb, unsigned short* __restrict__ O, int S) {
  __shared__ __align__(16) unsigned short sK[2][128 * 64];      // 128 keys x 64 d
  __shared__ __align__(16) unsigned short sV[2][2][64 * 64];    // [buf][half][64 d][64 slots]
  const int tid = threadIdx.x, lane = tid & 63, wid = tid >> 6;
  const int rr = lane & 15, g = lane >> 4;
  const int nqt = S / 128;
  const int cpx = gridDim.x >> 3;
  const int swz = (blockIdx.x & 7) * cpx + (blockIdx.x >> 3);
  const int qt = swz % nqt;
  const int bh = swz / nqt;
  const int h = bh & (NHEAD - 1), b = bh / NHEAD;

  const unsigned short* Qbase = QKV + ((size_t)b * S + qt * 128 + wid * 32) * QLD + h * DK;
  const unsigned short* Kbase = QKV + (size_t)b * S * QLD + DM + h * DK;
  const unsigned short* Vbase = Vt + (size_t)bh * DK * S;

  bf16x8 aq[2][2];
#pragma unroll
  for (int qm = 0; qm < 2; ++qm) {
    aq[qm][0] = *(const bf16x8*)&Qbase[(size_t)(qm * 16 + rr) * QLD + g * 8];
    aq[qm][1] = *(const bf16x8*)&Qbase[(size_t)(qm * 16 + rr) * QLD + 32 + g * 8];
  }

  f32x4 acc[2][5] = {};
  const f32x4 z0 = {};

  auto stage = [&](int buf, int kt) {
    // K: 128 rows x 128B, 1024 chunks
#pragma unroll
    for (int j = 0; j < 4; ++j) {
      int o = j * 256 + tid;
      int row = o >> 3;
      int cb = ((o & 7) * 16) ^ ((row & 7) << 4);
      gld16((const char*)(Kbase + (size_t)(kt * 128 + row) * QLD) + cb, &sK[buf][o * 8]);
    }
    // V: 2 halves x (64 rows x 128B), 1024 chunks; dest stays linear (o*8)
#pragma unroll
    for (int j = 0; j < 4; ++j) {
      int o = j * 256 + tid;
      int half_ = o >> 9;
      int r = o & 511;
      int row = r >> 3;
      int cb = ((r & 7) * 16) ^ ((row & 7) << 4);
      gld16((const char*)(Vbase + (size_t)row * S + kt * 128 + half_ * 64) + cb,
            &sV[buf][0][o * 8]);
    }
  };

  stage(0, 0);
  int cur = 0;
  const int nkt = S / 128;
  const int swr = (rr & 7) << 4;   // row&7 == rr&7 for all frag rows
  for (int kt = 0; kt < nkt; ++kt) {
    __syncthreads();
    if (kt + 1 < nkt) stage(cur ^ 1, kt + 1);

#pragma unroll
    for (int half = 0; half < 2; ++half) {
      // ---- hoisted loads: K frags, V frags, tw frags all issued up front ----
      bf16x8 kA[4][2];
#pragma unroll
      for (int f = 0; f < 4; ++f) {
        const int row = half * 64 + f * 16 + rr;
        kA[f][0] = *(const bf16x8*)((const char*)&sK[cur][row * 64] + ((g * 16) ^ swr));
        kA[f][1] = *(const bf16x8*)((const char*)&sK[cur][row * 64] + ((64 + g * 16) ^ swr));
      }
      bf16x8 vB[2][4];
#pragma unroll
      for (int kk = 0; kk < 2; ++kk)
#pragma unroll
        for (int n = 0; n < 4; ++n) {
          const int vrow = n * 16 + rr;
          const int cb = (kk * 64 + g * 16) ^ ((vrow & 7) << 4);
          vB[kk][n] = *(const bf16x8*)((const char*)&sV[cur][half][vrow * 64] + cb);
        }
      bf16x8 tw0 = *(const bf16x8*)&twb[kt * 128 + half * 64 + g * 8];
      bf16x8 tw1 = *(const bf16x8*)&twb[kt * 128 + half * 64 + 32 + g * 8];

      // ---- swapped scores: s[qm][f] = P[key=16f+4g+r][q=qm*16+rr] ----
      f32x4 s[2][4];
      __builtin_amdgcn_s_setprio(1);
#pragma unroll
      for (int f = 0; f < 4; ++f)
#pragma unroll
        for (int qm = 0; qm < 2; ++qm) {
          f32x4 z = __builtin_amdgcn_mfma_f32_16x16x32_bf16(kA[f][0], aq[qm][0], z0, 0, 0, 0);
          s[qm][f] = __builtin_amdgcn_mfma_f32_16x16x32_bf16(kA[f][1], aq[qm][1], z, 0, 0, 0);
        }
      __builtin_amdgcn_s_setprio(0);

      // ---- p = exp2(s) in place (lane-local) ----
#pragma unroll
      for (int qm = 0; qm < 2; ++qm)
#pragma unroll
        for (int f = 0; f < 4; ++f)
#pragma unroll
          for (int r = 0; r < 4; ++r)
            s[qm][f][r] = fexp2(s[qm][f][r]);

      // ---- pack P into A-frags: slot kk*32+g*8+j -> (f=2kk+(j>>2), r=j&3) ----
      bf16x8 pa[2][2];
#pragma unroll
      for (int qm = 0; qm < 2; ++qm)
#pragma unroll
        for (int kk = 0; kk < 2; ++kk) {
          union { bf16x8 v; unsigned u[4]; } pk;
          asm("v_cvt_pk_bf16_f32 %0, %1, %2" : "=v"(pk.u[0]) : "v"(s[qm][2*kk][0]),   "v"(s[qm][2*kk][1]));
          asm("v_cvt_pk_bf16_f32 %0, %1, %2" : "=v"(pk.u[1]) : "v"(s[qm][2*kk][2]),   "v"(s[qm][2*kk][3]));
          asm("v_cvt_pk_bf16_f32 %0, %1, %2" : "=v"(pk.u[2]) : "v"(s[qm][2*kk+1][0]), "v"(s[qm][2*kk+1][1]));
          asm("v_cvt_pk_bf16_f32 %0, %1, %2" : "=v"(pk.u[3]) : "v"(s[qm][2*kk+1][2]), "v"(s[qm][2*kk+1][3]));
          pa[qm][kk] = pk.v;
        }

      // ---- PV + denominator (V frags already in registers) ----
      __builtin_amdgcn_s_setprio(1);
#pragma unroll
      for (int kk = 0; kk < 2; ++kk) {
#pragma unroll
        for (int n = 0; n < 4; ++n)
#pragma unroll
          for (int qm = 0; qm < 2; ++qm)
            acc[qm][n] = __builtin_amdgcn_mfma_f32_16x16x32_bf16(pa[qm][kk], vB[kk][n], acc[qm][n], 0, 0, 0);
#pragma unroll
        for (int qm = 0; qm < 2; ++qm)
          acc[qm][4] = __builtin_amdgcn_mfma_f32_16x16x32_bf16(pa[qm][kk], kk ? tw1 : tw0, acc[qm][4], 0, 0, 0);
      }
      __builtin_amdgcn_s_setprio(0);
    }
    cur ^= 1;
  }

  // ---- coalesced epilogue: restage O tile (128 x 64 bf16) in LDS, 16B/lane stores ----
  unsigned short* L = &sK[0][0];   // 128*72 = 9216 shorts <= 16384 (sK region)
  __syncthreads();                 // all waves done reading sK/sV
#pragma unroll
  for (int qm = 0; qm < 2; ++qm)
#pragma unroll
    for (int n = 0; n < 4; ++n)
#pragma unroll
      for (int r = 0; r < 4; ++r)
        L[(wid * 32 + qm * 16 + g * 4 + r) * 72 + n * 16 + rr] =
            f2bf(acc[qm][n][r] / acc[qm][4][r]);
  __syncthreads();
  unsigned short* Ob = O + ((size_t)b * S + qt * 128) * DM + h * DK;
#pragma unroll
  for (int i = 0; i < 4; ++i) {
    int o = i * 256 + tid;         // 1024 chunks: 128 rows x 8 chunks of 16B
    int row = o >> 3;
    int c = (o & 7) * 8;
    uint4 v = *(const uint4*)&L[row * 72 + c];
    *(uint4*)&Ob[(size_t)row * DM + c] = v;
  }
}

// ---------------- launch ----------------
extern "C" void kernel_launch(void* const* d_in, const int* in_sizes, int n_in,
                              void* d_out, int out_size, void* d_ws, size_t ws_size,
                              hipStream_t stream) {
  const float* x      = (const float*)d_in[0];
  const float* coords = (const float*)d_in[1];
  const float* Wq = (const float*)d_in[2];
  const float* bq = (const float*)d_in[3];
  const float* Wk = (const float*)d_in[4];
  const float* bk = (const float*)d_in[5];
  const float* Wv = (const float*)d_in[6];
  const float* bv = (const float*)d_in[7];
  const float* Wo = (const float*)d_in[8];
  const float* bo = (const float*)d_in[9];

  const int S = in_sizes[1];
  const int B = in_sizes[0] / (S * DM);
  const int M = B * S;
  const float QS = 0.18033688011112042f;   // log2(e)/8

  char* w = (char*)d_ws;
  size_t off = 0;
  unsigned short* xb   = (unsigned short*)(w + off); off += (size_t)M * DM * 2;
  unsigned short* Wcat = (unsigned short*)(w + off); off += (size_t)3 * DM * DM * 2;
  unsigned short* Wob  = (unsigned short*)(w + off); off += (size_t)DM * DM * 2;
  unsigned short* QKVb = (unsigned short*)(w + off); off += (size_t)M * QLD * 2;
  unsigned short* Vtb  = (unsigned short*)(w + off); off += (size_t)M * DM * 2;
  float* tw  = (float*)(w + off); off += (size_t)S * 4;
  unsigned short* twb = (unsigned short*)(w + off); off += (size_t)S * 2;
  float* bcat = (float*)(w + off); off += (size_t)3 * DM * 4;
  unsigned short* Ob = xb;   // alias: xb dead after QKV gemm
  (void)ws_size; (void)n_in; (void)out_size;

  // fused prep (x conv, 4 weight convs, bias cat, tw) — one launch
  {
    int nx = M * DM / 4, nw = DM * DM / 4;
    int total = nx + 4 * nw;
    int tail = 3 * DM + S;
    int gridp = total / 256 + (tail + 255) / 256;
    k_prep<<<gridp, 256, 0, stream>>>(x, Wq, Wk, Wv, Wo, bq, bk, bv, coords,
                                      xb, Wcat, Wob, bcat, tw, twb, M, S, QS);
  }

  // fused QKV projection: [M,1024] x [3072,1024]^T -> [M,3072]
  // V-range blocks write Vt directly (transpose + tw + kappa) — no k_transpose kernel.
  gemm_bt<1><<<(M / BM) * (3 * DM / BN), 256, 0, stream>>>(
      xb, Wcat, bcat, QKVb, M, 3 * DM, DM, QLD, tw, Vtb, S);

  // attention
  k_attn<<<B * NHEAD * (S / 128), 256, 0, stream>>>(QKVb, Vtb, twb, Ob, S);

  // output projection (f32 out, 64x128 tile, 512 blocks)
  gemm_wo<<<(M / WBM) * (DM / BN), 256, 0, stream>>>(Ob, Wob, bo, (float*)d_out, M, DM, DM, DM);
}